// Round 1
// baseline (440.974 us; speedup 1.0000x reference)
//
#include <hip/hip_runtime.h>

#define CAP 40

// ---------------- small utility kernels ----------------

__global__ __launch_bounds__(256) void k_init(float* deg, int* cnt, int n) {
    int i = blockIdx.x * 256 + threadIdx.x;
    if (i < n) { deg[i] = 1.0f; cnt[i] = 0; }   // deg starts at 1: self loop
}

// one pass over edges: degree over col (+ bucket fill over row)
__global__ __launch_bounds__(256) void k_edge(const int* __restrict__ row, const int* __restrict__ col,
                                              float* deg, int* cnt, int* bucket, int ne) {
    int e = blockIdx.x * 256 + threadIdx.x;
    if (e >= ne) return;
    int r = row[e], c = col[e];
    atomicAdd(&deg[c], 1.0f);
    int pos = atomicAdd(&cnt[r], 1);
    if (pos < CAP) bucket[r * CAP + pos] = c;
}

__global__ __launch_bounds__(256) void k_edge_deg(const int* __restrict__ col, float* deg, int ne) {
    int e = blockIdx.x * 256 + threadIdx.x;
    if (e >= ne) return;
    atomicAdd(&deg[col[e]], 1.0f);
}

__global__ __launch_bounds__(256) void k_dinv(float* deg, int n) {
    int i = blockIdx.x * 256 + threadIdx.x;
    if (i < n) deg[i] = rsqrtf(deg[i]);          // deg >= 1 always (self loops)
}

// ---------------- GEMM: Y[n, :] = X[n, :] @ W + B, 128x128 W ----------------

__device__ __forceinline__ float4 f4fma(float4 a, float s, float4 b) {
    a.x = fmaf(s, b.x, a.x); a.y = fmaf(s, b.y, a.y);
    a.z = fmaf(s, b.z, a.z); a.w = fmaf(s, b.w, a.w);
    return a;
}

__global__ __launch_bounds__(256) void k_gemm(const float* __restrict__ X, const float* __restrict__ W,
                                              const float* __restrict__ B, float* __restrict__ Y, int nrows) {
    __shared__ float Ws[128 * 128];      // 64 KB
    __shared__ float Xs[32 * 128];       // 16 KB  (80 KB total, OK on gfx950: 160 KB/CU)
    int t = threadIdx.x;
    const float4* W4 = (const float4*)W;
    float4* Ws4 = (float4*)Ws;
#pragma unroll
    for (int i = 0; i < 16; ++i) Ws4[t + 256 * i] = W4[t + 256 * i];

    long base = (long)blockIdx.x * 32;
    const float4* X4 = (const float4*)X;
    float4* Xs4 = (float4*)Xs;
#pragma unroll
    for (int i = 0; i < 4; ++i) {
        int f = t + 256 * i;                 // float4 index within 32x128 tile
        long grow = base + (f >> 5);
        float4 v = make_float4(0.f, 0.f, 0.f, 0.f);
        if (grow < nrows) v = X4[grow * 32 + (f & 31)];
        Xs4[f] = v;
    }
    __syncthreads();

    int cq = t & 31;       // col quad: cols [cq*4, cq*4+4)
    int ng = t >> 5;       // node group: nodes [ng*4, ng*4+4) within tile
    float4 bias = ((const float4*)B)[cq];
    float4 acc0 = bias, acc1 = bias, acc2 = bias, acc3 = bias;
    int xr = ng * 4;

#pragma unroll 4
    for (int k = 0; k < 128; k += 4) {
        float4 x0 = Xs4[(xr + 0) * 32 + (k >> 2)];
        float4 x1 = Xs4[(xr + 1) * 32 + (k >> 2)];
        float4 x2 = Xs4[(xr + 2) * 32 + (k >> 2)];
        float4 x3 = Xs4[(xr + 3) * 32 + (k >> 2)];
        float4 w0 = Ws4[(k + 0) * 32 + cq];
        float4 w1 = Ws4[(k + 1) * 32 + cq];
        float4 w2 = Ws4[(k + 2) * 32 + cq];
        float4 w3 = Ws4[(k + 3) * 32 + cq];
        acc0 = f4fma(f4fma(f4fma(f4fma(acc0, x0.x, w0), x0.y, w1), x0.z, w2), x0.w, w3);
        acc1 = f4fma(f4fma(f4fma(f4fma(acc1, x1.x, w0), x1.y, w1), x1.z, w2), x1.w, w3);
        acc2 = f4fma(f4fma(f4fma(f4fma(acc2, x2.x, w0), x2.y, w1), x2.z, w2), x2.w, w3);
        acc3 = f4fma(f4fma(f4fma(f4fma(acc3, x3.x, w0), x3.y, w1), x3.z, w2), x3.w, w3);
    }

    float4* Y4 = (float4*)Y;
#pragma unroll
    for (int i = 0; i < 4; ++i) {
        long grow = base + xr + i;
        if (grow < nrows) {
            float4 a = (i == 0) ? acc0 : (i == 1) ? acc1 : (i == 2) ? acc2 : acc3;
            Y4[grow * 32 + cq] = a;
        }
    }
}

// ---------------- aggregation: out[n] = dinv[n]^2*h[n] + sum_e dinv[n]*dinv[c]*h[c] ----------------

__global__ __launch_bounds__(256) void k_agg(const float* __restrict__ h, const float* __restrict__ dinv,
                                             const int* __restrict__ cnt, const int* __restrict__ bucket,
                                             float* __restrict__ out, int n, int do_relu) {
    int wid = threadIdx.x >> 6, lane = threadIdx.x & 63;
    int nd = blockIdx.x * 4 + wid;
    if (nd >= n) return;
    float di = dinv[nd];
    const float2* h2 = (const float2*)h;
    float2 v = h2[(long)nd * 64 + lane];
    float2 acc;
    acc.x = di * di * v.x;
    acc.y = di * di * v.y;
    int m = cnt[nd]; if (m > CAP) m = CAP;
    const int* bk = bucket + (long)nd * CAP;
    for (int j = 0; j < m; ++j) {
        int c = bk[j];
        float nrm = di * dinv[c];
        float2 u = h2[(long)c * 64 + lane];
        acc.x = fmaf(nrm, u.x, acc.x);
        acc.y = fmaf(nrm, u.y, acc.y);
    }
    if (do_relu) { acc.x = fmaxf(acc.x, 0.f); acc.y = fmaxf(acc.y, 0.f); }
    ((float2*)out)[(long)nd * 64 + lane] = acc;
}

// ---------------- atomic-scatter fallback (only if ws too small for buckets) ----------------

__global__ __launch_bounds__(256) void k_selfinit(const float* __restrict__ h, const float* __restrict__ dinv,
                                                  float* __restrict__ g, int n) {
    long i = (long)blockIdx.x * 256 + threadIdx.x;   // over n*64 float2
    if (i >= (long)n * 64) return;
    int node = (int)(i >> 6);
    float d = dinv[node];
    float2 v = ((const float2*)h)[i];
    float2 o; o.x = d * d * v.x; o.y = d * d * v.y;
    ((float2*)g)[i] = o;
}

__global__ __launch_bounds__(256) void k_scatter(const int* __restrict__ row, const int* __restrict__ col,
                                                 const float* __restrict__ dinv, const float* __restrict__ h,
                                                 float* __restrict__ g, int ne) {
    int e = blockIdx.x * 4 + (threadIdx.x >> 6);
    int lane = threadIdx.x & 63;
    if (e >= ne) return;
    int r = row[e], c = col[e];
    float nrm = dinv[r] * dinv[c];
    float2 u = ((const float2*)h)[(long)c * 64 + lane];
    atomicAdd(&g[(long)r * 128 + lane * 2], nrm * u.x);
    atomicAdd(&g[(long)r * 128 + lane * 2 + 1], nrm * u.y);
}

__global__ __launch_bounds__(256) void k_relu(float* g, long n) {
    long i = (long)blockIdx.x * 256 + threadIdx.x;
    if (i < n) g[i] = fmaxf(g[i], 0.f);
}

// ---------------- mean pool per graph (batch is sorted) ----------------

__global__ __launch_bounds__(128) void k_pool(const float* __restrict__ g, const int* __restrict__ batch,
                                              int n, float* __restrict__ out) {
    int gid = blockIdx.x, t = threadIdx.x;
    int lo = 0, hi = n;
    while (lo < hi) { int m = (lo + hi) >> 1; if (batch[m] < gid) lo = m + 1; else hi = m; }
    int s = lo;
    hi = n;
    while (lo < hi) { int m = (lo + hi) >> 1; if (batch[m] < gid + 1) lo = m + 1; else hi = m; }
    int e2 = lo;
    float acc = 0.f;
    for (int i = s; i < e2; ++i) acc += g[(long)i * 128 + t];
    float c = (float)(e2 - s);
    out[gid * 128 + t] = acc / fmaxf(c, 1.0f);
}

// ---------------- host ----------------

extern "C" void kernel_launch(void* const* d_in, const int* in_sizes, int n_in,
                              void* d_out, int out_size, void* d_ws, size_t ws_size,
                              hipStream_t stream) {
    const float* x  = (const float*)d_in[0];
    const int* ei   = (const int*)d_in[1];
    const int* batch = (const int*)d_in[2];
    const float* W1 = (const float*)d_in[4];
    const float* b1 = (const float*)d_in[5];
    const float* W2 = (const float*)d_in[6];
    const float* b2 = (const float*)d_in[7];

    int N = in_sizes[0] / 128;
    int E = in_sizes[1] / 2;
    const int* row = ei;
    const int* col = ei + E;
    int G = out_size / 128;

    char* ws = (char*)d_ws;
    size_t off = 0;
    auto alloc = [&](size_t bytes) -> void* {
        void* p = ws + off;
        off += (bytes + 255) & ~(size_t)255;
        return p;
    };
    float* dinv = (float*)alloc((size_t)N * 4);
    int* cnt    = (int*)alloc((size_t)N * 4);
    float* h    = (float*)alloc((size_t)N * 512);
    float* g    = (float*)alloc((size_t)N * 512);
    size_t bucket_bytes = (size_t)N * CAP * 4;
    bool use_bucket = (off + bucket_bytes) <= ws_size;
    int* bucket = use_bucket ? (int*)alloc(bucket_bytes) : nullptr;

    int nbN = (N + 255) / 256;
    int nbE = (E + 255) / 256;

    k_init<<<nbN, 256, 0, stream>>>(dinv, cnt, N);
    if (use_bucket)
        k_edge<<<nbE, 256, 0, stream>>>(row, col, dinv, cnt, bucket, E);
    else
        k_edge_deg<<<nbE, 256, 0, stream>>>(col, dinv, E);
    k_dinv<<<nbN, 256, 0, stream>>>(dinv, N);

    int gemm_blocks = (N + 31) / 32;
    int agg_blocks  = (N + 3) / 4;

    // layer 1
    k_gemm<<<gemm_blocks, 256, 0, stream>>>(x, W1, b1, h, N);
    if (use_bucket) {
        k_agg<<<agg_blocks, 256, 0, stream>>>(h, dinv, cnt, bucket, g, N, 1);
    } else {
        k_selfinit<<<(int)(((long)N * 64 + 255) / 256), 256, 0, stream>>>(h, dinv, g, N);
        k_scatter<<<(E + 3) / 4, 256, 0, stream>>>(row, col, dinv, h, g, E);
        k_relu<<<(int)(((long)N * 128 + 255) / 256), 256, 0, stream>>>(g, (long)N * 128);
    }

    // layer 2
    k_gemm<<<gemm_blocks, 256, 0, stream>>>(g, W2, b2, h, N);
    if (use_bucket) {
        k_agg<<<agg_blocks, 256, 0, stream>>>(h, dinv, cnt, bucket, g, N, 0);
    } else {
        k_selfinit<<<(int)(((long)N * 64 + 255) / 256), 256, 0, stream>>>(h, dinv, g, N);
        k_scatter<<<(E + 3) / 4, 256, 0, stream>>>(row, col, dinv, h, g, E);
    }

    // mean pool
    k_pool<<<G, 128, 0, stream>>>(g, batch, N, (float*)d_out);
}

// Round 2
// 348.424 us; speedup vs baseline: 1.2656x; 1.2656x over previous
//
#include <hip/hip_runtime.h>

#define CAP 40
#define POOL_S 8

// ---------------- small utility kernels ----------------

__global__ __launch_bounds__(256) void k_init(float* deg, int* cnt, int n) {
    int i = blockIdx.x * 256 + threadIdx.x;
    if (i < n) { deg[i] = 1.0f; cnt[i] = 0; }   // deg starts at 1: self loop
}

// one pass over edges: degree over col (+ bucket fill over row)
__global__ __launch_bounds__(256) void k_edge(const int* __restrict__ row, const int* __restrict__ col,
                                              float* deg, int* cnt, int* bucket, int ne) {
    int e = blockIdx.x * 256 + threadIdx.x;
    if (e >= ne) return;
    int r = row[e], c = col[e];
    atomicAdd(&deg[c], 1.0f);
    int pos = atomicAdd(&cnt[r], 1);
    if (pos < CAP) bucket[r * CAP + pos] = c;
}

__global__ __launch_bounds__(256) void k_edge_deg(const int* __restrict__ col, float* deg, int ne) {
    int e = blockIdx.x * 256 + threadIdx.x;
    if (e >= ne) return;
    atomicAdd(&deg[col[e]], 1.0f);
}

__global__ __launch_bounds__(256) void k_dinv(float* deg, int n) {
    int i = blockIdx.x * 256 + threadIdx.x;
    if (i < n) deg[i] = rsqrtf(deg[i]);          // deg >= 1 always (self loops)
}

// ---------------- GEMM: Y[n, :] = X[n, :] @ W + B, 128x128 W ----------------

__device__ __forceinline__ float4 f4fma(float4 a, float s, float4 b) {
    a.x = fmaf(s, b.x, a.x); a.y = fmaf(s, b.y, a.y);
    a.z = fmaf(s, b.z, a.z); a.w = fmaf(s, b.w, a.w);
    return a;
}

__global__ __launch_bounds__(256) void k_gemm(const float* __restrict__ X, const float* __restrict__ W,
                                              const float* __restrict__ B, float* __restrict__ Y, int nrows) {
    __shared__ float Ws[128 * 128];      // 64 KB
    __shared__ float Xs[32 * 128];       // 16 KB  (80 KB total, OK on gfx950: 160 KB/CU)
    int t = threadIdx.x;
    const float4* W4 = (const float4*)W;
    float4* Ws4 = (float4*)Ws;
#pragma unroll
    for (int i = 0; i < 16; ++i) Ws4[t + 256 * i] = W4[t + 256 * i];

    long base = (long)blockIdx.x * 32;
    const float4* X4 = (const float4*)X;
    float4* Xs4 = (float4*)Xs;
#pragma unroll
    for (int i = 0; i < 4; ++i) {
        int f = t + 256 * i;                 // float4 index within 32x128 tile
        long grow = base + (f >> 5);
        float4 v = make_float4(0.f, 0.f, 0.f, 0.f);
        if (grow < nrows) v = X4[grow * 32 + (f & 31)];
        Xs4[f] = v;
    }
    __syncthreads();

    int cq = t & 31;       // col quad: cols [cq*4, cq*4+4)
    int ng = t >> 5;       // node group: nodes [ng*4, ng*4+4) within tile
    float4 bias = ((const float4*)B)[cq];
    float4 acc0 = bias, acc1 = bias, acc2 = bias, acc3 = bias;
    int xr = ng * 4;

#pragma unroll 4
    for (int k = 0; k < 128; k += 4) {
        float4 x0 = Xs4[(xr + 0) * 32 + (k >> 2)];
        float4 x1 = Xs4[(xr + 1) * 32 + (k >> 2)];
        float4 x2 = Xs4[(xr + 2) * 32 + (k >> 2)];
        float4 x3 = Xs4[(xr + 3) * 32 + (k >> 2)];
        float4 w0 = Ws4[(k + 0) * 32 + cq];
        float4 w1 = Ws4[(k + 1) * 32 + cq];
        float4 w2 = Ws4[(k + 2) * 32 + cq];
        float4 w3 = Ws4[(k + 3) * 32 + cq];
        acc0 = f4fma(f4fma(f4fma(f4fma(acc0, x0.x, w0), x0.y, w1), x0.z, w2), x0.w, w3);
        acc1 = f4fma(f4fma(f4fma(f4fma(acc1, x1.x, w0), x1.y, w1), x1.z, w2), x1.w, w3);
        acc2 = f4fma(f4fma(f4fma(f4fma(acc2, x2.x, w0), x2.y, w1), x2.z, w2), x2.w, w3);
        acc3 = f4fma(f4fma(f4fma(f4fma(acc3, x3.x, w0), x3.y, w1), x3.z, w2), x3.w, w3);
    }

    float4* Y4 = (float4*)Y;
#pragma unroll
    for (int i = 0; i < 4; ++i) {
        long grow = base + xr + i;
        if (grow < nrows) {
            float4 a = (i == 0) ? acc0 : (i == 1) ? acc1 : (i == 2) ? acc2 : acc3;
            Y4[grow * 32 + cq] = a;
        }
    }
}

// ---------------- aggregation: out[n] = dinv[n]^2*h[n] + sum_e dinv[n]*dinv[c]*h[c] ----------------

__global__ __launch_bounds__(256) void k_agg(const float* __restrict__ h, const float* __restrict__ dinv,
                                             const int* __restrict__ cnt, const int* __restrict__ bucket,
                                             float* __restrict__ out, int n, int do_relu) {
    int wid = threadIdx.x >> 6, lane = threadIdx.x & 63;
    int nd = blockIdx.x * 4 + wid;
    if (nd >= n) return;
    float di = dinv[nd];
    const float2* h2 = (const float2*)h;
    float2 v = h2[(long)nd * 64 + lane];
    float2 acc;
    acc.x = di * di * v.x;
    acc.y = di * di * v.y;
    int m = cnt[nd]; if (m > CAP) m = CAP;
    const int* bk = bucket + (long)nd * CAP;
    for (int j = 0; j < m; ++j) {
        int c = bk[j];
        float nrm = di * dinv[c];
        float2 u = h2[(long)c * 64 + lane];
        acc.x = fmaf(nrm, u.x, acc.x);
        acc.y = fmaf(nrm, u.y, acc.y);
    }
    if (do_relu) { acc.x = fmaxf(acc.x, 0.f); acc.y = fmaxf(acc.y, 0.f); }
    ((float2*)out)[(long)nd * 64 + lane] = acc;
}

// ---------------- atomic-scatter fallback (only if ws too small for buckets) ----------------

__global__ __launch_bounds__(256) void k_selfinit(const float* __restrict__ h, const float* __restrict__ dinv,
                                                  float* __restrict__ g, int n) {
    long i = (long)blockIdx.x * 256 + threadIdx.x;   // over n*64 float2
    if (i >= (long)n * 64) return;
    int node = (int)(i >> 6);
    float d = dinv[node];
    float2 v = ((const float2*)h)[i];
    float2 o; o.x = d * d * v.x; o.y = d * d * v.y;
    ((float2*)g)[i] = o;
}

__global__ __launch_bounds__(256) void k_scatter(const int* __restrict__ row, const int* __restrict__ col,
                                                 const float* __restrict__ dinv, const float* __restrict__ h,
                                                 float* __restrict__ g, int ne) {
    int e = blockIdx.x * 4 + (threadIdx.x >> 6);
    int lane = threadIdx.x & 63;
    if (e >= ne) return;
    int r = row[e], c = col[e];
    float nrm = dinv[r] * dinv[c];
    float2 u = ((const float2*)h)[(long)c * 64 + lane];
    atomicAdd(&g[(long)r * 128 + lane * 2], nrm * u.x);
    atomicAdd(&g[(long)r * 128 + lane * 2 + 1], nrm * u.y);
}

__global__ __launch_bounds__(256) void k_relu(float* g, long n) {
    long i = (long)blockIdx.x * 256 + threadIdx.x;
    if (i < n) g[i] = fmaxf(g[i], 0.f);
}

// ---------------- mean pool per graph (batch is sorted), two-stage ----------------
// Stage A: G*POOL_S blocks, 256 thr = 8 row-lanes x 32 float4-col-quads.
// A wave reads 2 full 512B node rows coalesced; 64-way row parallelism per graph.
__global__ __launch_bounds__(256) void k_pool_partial(const float* __restrict__ g, const int* __restrict__ batch,
                                                      int n, float* __restrict__ partial, int* __restrict__ cntg) {
    int gid = blockIdx.x >> 3;      // POOL_S = 8
    int s   = blockIdx.x & 7;
    int t = threadIdx.x;
    int lo = 0, hi = n;
    while (lo < hi) { int m = (lo + hi) >> 1; if (batch[m] < gid) lo = m + 1; else hi = m; }
    int s0 = lo;
    hi = n;
    while (lo < hi) { int m = (lo + hi) >> 1; if (batch[m] < gid + 1) lo = m + 1; else hi = m; }
    int e0 = lo;
    if (s == 0 && t == 0) cntg[gid] = e0 - s0;

    int cq = t & 31, rl = t >> 5;
    const float4* g4 = (const float4*)g;
    float4 acc = make_float4(0.f, 0.f, 0.f, 0.f);
    for (int i = s0 + s * 8 + rl; i < e0; i += 64) {
        float4 v = g4[(long)i * 32 + cq];
        acc.x += v.x; acc.y += v.y; acc.z += v.z; acc.w += v.w;
    }
    __shared__ float4 red[256];
    red[t] = acc;
    __syncthreads();
    if (t < 32) {
        float4 a = red[t];
#pragma unroll
        for (int r = 1; r < 8; ++r) {
            float4 b = red[r * 32 + t];
            a.x += b.x; a.y += b.y; a.z += b.z; a.w += b.w;
        }
        ((float4*)partial)[(long)blockIdx.x * 32 + t] = a;
    }
}

__global__ __launch_bounds__(256) void k_pool_final(const float* __restrict__ partial, const int* __restrict__ cntg,
                                                    int ng, float* __restrict__ out) {
    int idx = blockIdx.x * 256 + threadIdx.x;   // over ng*128
    if (idx >= ng * 128) return;
    int gid = idx >> 7, col = idx & 127;
    float a = 0.f;
#pragma unroll
    for (int s = 0; s < POOL_S; ++s) a += partial[(long)(gid * POOL_S + s) * 128 + col];
    out[idx] = a / fmaxf((float)cntg[gid], 1.0f);
}

// ---------------- host ----------------

extern "C" void kernel_launch(void* const* d_in, const int* in_sizes, int n_in,
                              void* d_out, int out_size, void* d_ws, size_t ws_size,
                              hipStream_t stream) {
    const float* x  = (const float*)d_in[0];
    const int* ei   = (const int*)d_in[1];
    const int* batch = (const int*)d_in[2];
    const float* W1 = (const float*)d_in[4];
    const float* b1 = (const float*)d_in[5];
    const float* W2 = (const float*)d_in[6];
    const float* b2 = (const float*)d_in[7];

    int N = in_sizes[0] / 128;
    int E = in_sizes[1] / 2;
    const int* row = ei;
    const int* col = ei + E;
    int G = out_size / 128;

    char* ws = (char*)d_ws;
    size_t off = 0;
    auto alloc = [&](size_t bytes) -> void* {
        void* p = ws + off;
        off += (bytes + 255) & ~(size_t)255;
        return p;
    };
    float* dinv = (float*)alloc((size_t)N * 4);
    int* cnt    = (int*)alloc((size_t)N * 4);
    float* h    = (float*)alloc((size_t)N * 512);
    float* g    = (float*)alloc((size_t)N * 512);
    float* partial = (float*)alloc((size_t)G * POOL_S * 128 * 4);
    int* cntg   = (int*)alloc((size_t)G * 4);
    size_t bucket_bytes = (size_t)N * CAP * 4;
    bool use_bucket = (off + bucket_bytes) <= ws_size;
    int* bucket = use_bucket ? (int*)alloc(bucket_bytes) : nullptr;

    int nbN = (N + 255) / 256;
    int nbE = (E + 255) / 256;

    k_init<<<nbN, 256, 0, stream>>>(dinv, cnt, N);
    if (use_bucket)
        k_edge<<<nbE, 256, 0, stream>>>(row, col, dinv, cnt, bucket, E);
    else
        k_edge_deg<<<nbE, 256, 0, stream>>>(col, dinv, E);
    k_dinv<<<nbN, 256, 0, stream>>>(dinv, N);

    int gemm_blocks = (N + 31) / 32;
    int agg_blocks  = (N + 3) / 4;

    // layer 1
    k_gemm<<<gemm_blocks, 256, 0, stream>>>(x, W1, b1, h, N);
    if (use_bucket) {
        k_agg<<<agg_blocks, 256, 0, stream>>>(h, dinv, cnt, bucket, g, N, 1);
    } else {
        k_selfinit<<<(int)(((long)N * 64 + 255) / 256), 256, 0, stream>>>(h, dinv, g, N);
        k_scatter<<<(E + 3) / 4, 256, 0, stream>>>(row, col, dinv, h, g, E);
        k_relu<<<(int)(((long)N * 128 + 255) / 256), 256, 0, stream>>>(g, (long)N * 128);
    }

    // layer 2
    k_gemm<<<gemm_blocks, 256, 0, stream>>>(g, W2, b2, h, N);
    if (use_bucket) {
        k_agg<<<agg_blocks, 256, 0, stream>>>(h, dinv, cnt, bucket, g, N, 0);
    } else {
        k_selfinit<<<(int)(((long)N * 64 + 255) / 256), 256, 0, stream>>>(h, dinv, g, N);
        k_scatter<<<(E + 3) / 4, 256, 0, stream>>>(row, col, dinv, h, g, E);
    }

    // mean pool: two-stage
    k_pool_partial<<<G * POOL_S, 256, 0, stream>>>(g, batch, N, partial, cntg);
    k_pool_final<<<(G * 128 + 255) / 256, 256, 0, stream>>>(partial, cntg, G, (float*)d_out);
}

// Round 3
// 275.129 us; speedup vs baseline: 1.6028x; 1.2664x over previous
//
#include <hip/hip_runtime.h>

#define CAP 40
#define POOL_S 8

typedef __bf16 bf16x8 __attribute__((ext_vector_type(8)));
typedef float f32x4 __attribute__((ext_vector_type(4)));

__device__ __forceinline__ unsigned short f2bf(float f) {
    unsigned u = __float_as_uint(f);
    unsigned r = u + 0x7FFFu + ((u >> 16) & 1u);
    return (unsigned short)(r >> 16);
}
__device__ __forceinline__ float bflo(unsigned u) { return __uint_as_float(u << 16); }
__device__ __forceinline__ float bfhi(unsigned u) { return __uint_as_float(u & 0xFFFF0000u); }

// ---------------- small utility kernels ----------------

__global__ __launch_bounds__(256) void k_init(float* deg, int* cnt, int n) {
    int i = blockIdx.x * 256 + threadIdx.x;
    if (i < n) { deg[i] = 1.0f; cnt[i] = 0; }   // deg starts at 1: self loop
}

__global__ __launch_bounds__(256) void k_edge(const int* __restrict__ row, const int* __restrict__ col,
                                              float* deg, int* cnt, int* bucket, int ne) {
    int e = blockIdx.x * 256 + threadIdx.x;
    if (e >= ne) return;
    int r = row[e], c = col[e];
    atomicAdd(&deg[c], 1.0f);
    int pos = atomicAdd(&cnt[r], 1);
    if (pos < CAP) bucket[r * CAP + pos] = c;
}

__global__ __launch_bounds__(256) void k_edge_deg(const int* __restrict__ col, float* deg, int ne) {
    int e = blockIdx.x * 256 + threadIdx.x;
    if (e >= ne) return;
    atomicAdd(&deg[col[e]], 1.0f);
}

__global__ __launch_bounds__(256) void k_dinv(float* deg, int n) {
    int i = blockIdx.x * 256 + threadIdx.x;
    if (i < n) deg[i] = rsqrtf(deg[i]);
}

// ---------------- W pre-pack: fp32 128x128 -> bf16 MFMA B-fragments ----------------
// slot = nt*4+kt (nt: 16-col tile, kt: 32-k tile); frag elem j of lane l:
//   W[kt*32 + (l>>4)*8 + j][nt*16 + (l&15)]
__global__ __launch_bounds__(256) void k_prepW(const float* __restrict__ W, uint4* __restrict__ Wp) {
    int t = blockIdx.x * 256 + threadIdx.x;
    if (t >= 2048) return;
    int slot = t >> 6, lane = t & 63;
    int nt = slot >> 2, kt = slot & 3;
    int kbase = kt * 32 + (lane >> 4) * 8;
    int colw = nt * 16 + (lane & 15);
    unsigned short e[8];
#pragma unroll
    for (int j = 0; j < 8; ++j) e[j] = f2bf(W[(kbase + j) * 128 + colw]);
    uint4 v;
    v.x = e[0] | ((unsigned)e[1] << 16);
    v.y = e[2] | ((unsigned)e[3] << 16);
    v.z = e[4] | ((unsigned)e[5] << 16);
    v.w = e[6] | ((unsigned)e[7] << 16);
    Wp[t] = v;
}

// ---------------- GEMM: Y_bf16[n,:] = bf16(X_f32[n,:]) @ W_bf16 + B, via MFMA ----------------
// Per wave: 16 rows x 128 cols. A lane l: row m0+(l&15), k = kt*32+(l>>4)*8+j.
// D lane l reg j: row m0+(l>>4)*4+j, col nt*16+(l&15). (m89-verified mapping)
__global__ __launch_bounds__(256) void k_gemm_mfma(const float* __restrict__ X,
        const float4* __restrict__ Wp, const float* __restrict__ Bias,
        unsigned short* __restrict__ Y, int nrows) {
    __shared__ float4 Wl[2048];   // 32 KB packed W fragments
    int t = threadIdx.x;
#pragma unroll
    for (int i = 0; i < 8; ++i) Wl[t + 256 * i] = Wp[t + 256 * i];
    __syncthreads();

    int wid = t >> 6, lane = t & 63;
    long m0 = ((long)blockIdx.x * 4 + wid) * 16;
    if (m0 >= nrows) return;
    int lr = lane & 15, lg = lane >> 4;
    long mr = m0 + lr; if (mr > (long)nrows - 1) mr = nrows - 1;
    const float* xrow = X + mr * 128 + lg * 8;

    bf16x8 a[4];
#pragma unroll
    for (int kt = 0; kt < 4; ++kt) {
        float4 lo = *(const float4*)(xrow + kt * 32);
        float4 hi = *(const float4*)(xrow + kt * 32 + 4);
        bf16x8 v;
        v[0] = (__bf16)lo.x; v[1] = (__bf16)lo.y; v[2] = (__bf16)lo.z; v[3] = (__bf16)lo.w;
        v[4] = (__bf16)hi.x; v[5] = (__bf16)hi.y; v[6] = (__bf16)hi.z; v[7] = (__bf16)hi.w;
        a[kt] = v;
    }

    const bf16x8* Wf = (const bf16x8*)Wl;
    f32x4 acc[8];
#pragma unroll
    for (int nt = 0; nt < 8; ++nt) acc[nt] = (f32x4)(0.0f);
#pragma unroll
    for (int nt = 0; nt < 8; ++nt) {
#pragma unroll
        for (int kt = 0; kt < 4; ++kt)
            acc[nt] = __builtin_amdgcn_mfma_f32_16x16x32_bf16(a[kt], Wf[(nt * 4 + kt) * 64 + lane], acc[nt], 0, 0, 0);
    }

#pragma unroll
    for (int nt = 0; nt < 8; ++nt) {
        float b = Bias[nt * 16 + lr];
#pragma unroll
        for (int j = 0; j < 4; ++j) {
            long r = m0 + lg * 4 + j;
            if (r < nrows) Y[r * 128 + nt * 16 + lr] = f2bf(acc[nt][j] + b);
        }
    }
}

// ---------------- aggregation over bf16 h: g_f32[n] = dinv[n]^2*h[n] + sum dinv[n]dinv[c]*h[c] ----------------

__global__ __launch_bounds__(256) void k_agg(const unsigned* __restrict__ hu, const float* __restrict__ dinv,
                                             const int* __restrict__ cnt, const int* __restrict__ bucket,
                                             float* __restrict__ out, int n, int do_relu) {
    int wid = threadIdx.x >> 6, lane = threadIdx.x & 63;
    int nd = blockIdx.x * 4 + wid;
    if (nd >= n) return;
    float di = dinv[nd];
    unsigned v = hu[(long)nd * 64 + lane];
    float2 acc;
    acc.x = di * di * bflo(v);
    acc.y = di * di * bfhi(v);
    int m = cnt[nd]; if (m > CAP) m = CAP;
    const int* bk = bucket + (long)nd * CAP;
    for (int j = 0; j < m; ++j) {
        int c = bk[j];
        float nrm = di * dinv[c];
        unsigned u = hu[(long)c * 64 + lane];
        acc.x = fmaf(nrm, bflo(u), acc.x);
        acc.y = fmaf(nrm, bfhi(u), acc.y);
    }
    if (do_relu) { acc.x = fmaxf(acc.x, 0.f); acc.y = fmaxf(acc.y, 0.f); }
    ((float2*)out)[(long)nd * 64 + lane] = acc;
}

// ---------------- atomic-scatter fallback (bf16 h) ----------------

__global__ __launch_bounds__(256) void k_selfinit(const unsigned* __restrict__ hu, const float* __restrict__ dinv,
                                                  float* __restrict__ g, int n) {
    long i = (long)blockIdx.x * 256 + threadIdx.x;
    if (i >= (long)n * 64) return;
    int node = (int)(i >> 6);
    float d = dinv[node];
    unsigned u = hu[i];
    float2 o; o.x = d * d * bflo(u); o.y = d * d * bfhi(u);
    ((float2*)g)[i] = o;
}

__global__ __launch_bounds__(256) void k_scatter(const int* __restrict__ row, const int* __restrict__ col,
                                                 const float* __restrict__ dinv, const unsigned* __restrict__ hu,
                                                 float* __restrict__ g, int ne) {
    int e = blockIdx.x * 4 + (threadIdx.x >> 6);
    int lane = threadIdx.x & 63;
    if (e >= ne) return;
    int r = row[e], c = col[e];
    float nrm = dinv[r] * dinv[c];
    unsigned u = hu[(long)c * 64 + lane];
    atomicAdd(&g[(long)r * 128 + lane * 2], nrm * bflo(u));
    atomicAdd(&g[(long)r * 128 + lane * 2 + 1], nrm * bfhi(u));
}

__global__ __launch_bounds__(256) void k_relu(float* g, long n) {
    long i = (long)blockIdx.x * 256 + threadIdx.x;
    if (i < n) g[i] = fmaxf(g[i], 0.f);
}

// ---------------- mean pool per graph (batch is sorted), two-stage ----------------

__global__ __launch_bounds__(256) void k_pool_partial(const float* __restrict__ g, const int* __restrict__ batch,
                                                      int n, float* __restrict__ partial, int* __restrict__ cntg) {
    int gid = blockIdx.x >> 3;
    int s   = blockIdx.x & 7;
    int t = threadIdx.x;
    int lo = 0, hi = n;
    while (lo < hi) { int m = (lo + hi) >> 1; if (batch[m] < gid) lo = m + 1; else hi = m; }
    int s0 = lo;
    hi = n;
    while (lo < hi) { int m = (lo + hi) >> 1; if (batch[m] < gid + 1) lo = m + 1; else hi = m; }
    int e0 = lo;
    if (s == 0 && t == 0) cntg[gid] = e0 - s0;

    int cq = t & 31, rl = t >> 5;
    const float4* g4 = (const float4*)g;
    float4 acc = make_float4(0.f, 0.f, 0.f, 0.f);
    for (int i = s0 + s * 8 + rl; i < e0; i += 64) {
        float4 v = g4[(long)i * 32 + cq];
        acc.x += v.x; acc.y += v.y; acc.z += v.z; acc.w += v.w;
    }
    __shared__ float4 red[256];
    red[t] = acc;
    __syncthreads();
    if (t < 32) {
        float4 a = red[t];
#pragma unroll
        for (int r = 1; r < 8; ++r) {
            float4 b = red[r * 32 + t];
            a.x += b.x; a.y += b.y; a.z += b.z; a.w += b.w;
        }
        ((float4*)partial)[(long)blockIdx.x * 32 + t] = a;
    }
}

__global__ __launch_bounds__(256) void k_pool_final(const float* __restrict__ partial, const int* __restrict__ cntg,
                                                    int ng, float* __restrict__ out) {
    int idx = blockIdx.x * 256 + threadIdx.x;
    if (idx >= ng * 128) return;
    int gid = idx >> 7, col = idx & 127;
    float a = 0.f;
#pragma unroll
    for (int s = 0; s < POOL_S; ++s) a += partial[(long)(gid * POOL_S + s) * 128 + col];
    out[idx] = a / fmaxf((float)cntg[gid], 1.0f);
}

// ---------------- host ----------------

extern "C" void kernel_launch(void* const* d_in, const int* in_sizes, int n_in,
                              void* d_out, int out_size, void* d_ws, size_t ws_size,
                              hipStream_t stream) {
    const float* x  = (const float*)d_in[0];
    const int* ei   = (const int*)d_in[1];
    const int* batch = (const int*)d_in[2];
    const float* W1 = (const float*)d_in[4];
    const float* b1 = (const float*)d_in[5];
    const float* W2 = (const float*)d_in[6];
    const float* b2 = (const float*)d_in[7];

    int N = in_sizes[0] / 128;
    int E = in_sizes[1] / 2;
    const int* row = ei;
    const int* col = ei + E;
    int G = out_size / 128;

    char* ws = (char*)d_ws;
    size_t off = 0;
    auto alloc = [&](size_t bytes) -> void* {
        void* p = ws + off;
        off += (bytes + 255) & ~(size_t)255;
        return p;
    };
    float* dinv = (float*)alloc((size_t)N * 4);
    int* cnt    = (int*)alloc((size_t)N * 4);
    unsigned short* h = (unsigned short*)alloc((size_t)N * 256);   // bf16 h
    float* g    = (float*)alloc((size_t)N * 512);                  // fp32 agg out
    float* partial = (float*)alloc((size_t)G * POOL_S * 128 * 4);
    int* cntg   = (int*)alloc((size_t)G * 4);
    uint4* wp1  = (uint4*)alloc(32768);
    uint4* wp2  = (uint4*)alloc(32768);
    size_t bucket_bytes = (size_t)N * CAP * 4;
    bool use_bucket = (off + bucket_bytes) <= ws_size;
    int* bucket = use_bucket ? (int*)alloc(bucket_bytes) : nullptr;

    int nbN = (N + 255) / 256;
    int nbE = (E + 255) / 256;

    k_init<<<nbN, 256, 0, stream>>>(dinv, cnt, N);
    if (use_bucket)
        k_edge<<<nbE, 256, 0, stream>>>(row, col, dinv, cnt, bucket, E);
    else
        k_edge_deg<<<nbE, 256, 0, stream>>>(col, dinv, E);
    k_dinv<<<nbN, 256, 0, stream>>>(dinv, N);
    k_prepW<<<8, 256, 0, stream>>>(W1, wp1);
    k_prepW<<<8, 256, 0, stream>>>(W2, wp2);

    int gemm_blocks = (N + 63) / 64;
    int agg_blocks  = (N + 3) / 4;

    // layer 1
    k_gemm_mfma<<<gemm_blocks, 256, 0, stream>>>(x, (const float4*)wp1, b1, h, N);
    if (use_bucket) {
        k_agg<<<agg_blocks, 256, 0, stream>>>((const unsigned*)h, dinv, cnt, bucket, g, N, 1);
    } else {
        k_selfinit<<<(int)(((long)N * 64 + 255) / 256), 256, 0, stream>>>((const unsigned*)h, dinv, g, N);
        k_scatter<<<(E + 3) / 4, 256, 0, stream>>>(row, col, dinv, (const unsigned*)h, g, E);
        k_relu<<<(int)(((long)N * 128 + 255) / 256), 256, 0, stream>>>(g, (long)N * 128);
    }

    // layer 2
    k_gemm_mfma<<<gemm_blocks, 256, 0, stream>>>(g, (const float4*)wp2, b2, h, N);
    if (use_bucket) {
        k_agg<<<agg_blocks, 256, 0, stream>>>((const unsigned*)h, dinv, cnt, bucket, g, N, 0);
    } else {
        k_selfinit<<<(int)(((long)N * 64 + 255) / 256), 256, 0, stream>>>((const unsigned*)h, dinv, g, N);
        k_scatter<<<(E + 3) / 4, 256, 0, stream>>>(row, col, dinv, (const unsigned*)h, g, E);
    }

    // mean pool: two-stage
    k_pool_partial<<<G * POOL_S, 256, 0, stream>>>(g, batch, N, partial, cntg);
    k_pool_final<<<(G * 128 + 255) / 256, 256, 0, stream>>>(partial, cntg, G, (float*)d_out);
}

// Round 4
// 229.915 us; speedup vs baseline: 1.9180x; 1.1967x over previous
//
#include <hip/hip_runtime.h>

#define CAP 40
#define POOL_S 8

typedef __bf16 bf16x8 __attribute__((ext_vector_type(8)));
typedef float f32x4 __attribute__((ext_vector_type(4)));

__device__ __forceinline__ unsigned short f2bf(float f) {
    unsigned u = __float_as_uint(f);
    unsigned r = u + 0x7FFFu + ((u >> 16) & 1u);
    return (unsigned short)(r >> 16);
}
__device__ __forceinline__ float bflo(unsigned u) { return __uint_as_float(u << 16); }
__device__ __forceinline__ float bfhi(unsigned u) { return __uint_as_float(u & 0xFFFF0000u); }

// ---------------- small utility kernels ----------------

__global__ __launch_bounds__(256) void k_init(float* deg, int* cnt, int n) {
    int i = blockIdx.x * 256 + threadIdx.x;
    if (i < n) { deg[i] = 1.0f; cnt[i] = 0; }   // deg starts at 1: self loop
}

__global__ __launch_bounds__(256) void k_edge(const int* __restrict__ row, const int* __restrict__ col,
                                              float* deg, int* cnt, int* bucket, int ne) {
    int e = blockIdx.x * 256 + threadIdx.x;
    if (e >= ne) return;
    int r = row[e], c = col[e];
    atomicAdd(&deg[c], 1.0f);
    int pos = atomicAdd(&cnt[r], 1);
    if (pos < CAP) bucket[r * CAP + pos] = c;
}

__global__ __launch_bounds__(256) void k_edge_deg(const int* __restrict__ col, float* deg, int ne) {
    int e = blockIdx.x * 256 + threadIdx.x;
    if (e >= ne) return;
    atomicAdd(&deg[col[e]], 1.0f);
}

__global__ __launch_bounds__(256) void k_dinv(float* deg, int n) {
    int i = blockIdx.x * 256 + threadIdx.x;
    if (i < n) deg[i] = rsqrtf(deg[i]);
}

// ---------------- W pre-pack: fp32 128x128 -> bf16 MFMA B-fragments ----------------

__global__ __launch_bounds__(256) void k_prepW(const float* __restrict__ W, uint4* __restrict__ Wp) {
    int t = blockIdx.x * 256 + threadIdx.x;
    if (t >= 2048) return;
    int slot = t >> 6, lane = t & 63;
    int nt = slot >> 2, kt = slot & 3;
    int kbase = kt * 32 + (lane >> 4) * 8;
    int colw = nt * 16 + (lane & 15);
    unsigned short e[8];
#pragma unroll
    for (int j = 0; j < 8; ++j) e[j] = f2bf(W[(kbase + j) * 128 + colw]);
    uint4 v;
    v.x = e[0] | ((unsigned)e[1] << 16);
    v.y = e[2] | ((unsigned)e[3] << 16);
    v.z = e[4] | ((unsigned)e[5] << 16);
    v.w = e[6] | ((unsigned)e[7] << 16);
    Wp[t] = v;
}

// ---------------- GEMM: Y_bf16 = A @ W_bf16 + B via MFMA; A fp32 or bf16 ----------------

template<int IN_BF16>
__global__ __launch_bounds__(256) void k_gemm_mfma(const void* __restrict__ Xv,
        const float4* __restrict__ Wp, const float* __restrict__ Bias,
        unsigned short* __restrict__ Y, int nrows) {
    __shared__ float4 Wl[2048];   // 32 KB packed W fragments
    int t = threadIdx.x;
#pragma unroll
    for (int i = 0; i < 8; ++i) Wl[t + 256 * i] = Wp[t + 256 * i];
    __syncthreads();

    int wid = t >> 6, lane = t & 63;
    long m0 = ((long)blockIdx.x * 4 + wid) * 16;
    if (m0 >= nrows) return;
    int lr = lane & 15, lg = lane >> 4;
    long mr = m0 + lr; if (mr > (long)nrows - 1) mr = nrows - 1;

    bf16x8 a[4];
    if (IN_BF16) {
        const unsigned short* xb = (const unsigned short*)Xv + mr * 128 + lg * 8;
#pragma unroll
        for (int kt = 0; kt < 4; ++kt) a[kt] = *(const bf16x8*)(xb + kt * 32);
    } else {
        const float* xrow = (const float*)Xv + mr * 128 + lg * 8;
#pragma unroll
        for (int kt = 0; kt < 4; ++kt) {
            float4 lo = *(const float4*)(xrow + kt * 32);
            float4 hi = *(const float4*)(xrow + kt * 32 + 4);
            bf16x8 v;
            v[0] = (__bf16)lo.x; v[1] = (__bf16)lo.y; v[2] = (__bf16)lo.z; v[3] = (__bf16)lo.w;
            v[4] = (__bf16)hi.x; v[5] = (__bf16)hi.y; v[6] = (__bf16)hi.z; v[7] = (__bf16)hi.w;
            a[kt] = v;
        }
    }

    const bf16x8* Wf = (const bf16x8*)Wl;
    f32x4 acc[8];
#pragma unroll
    for (int nt = 0; nt < 8; ++nt) acc[nt] = (f32x4)(0.0f);
#pragma unroll
    for (int nt = 0; nt < 8; ++nt) {
#pragma unroll
        for (int kt = 0; kt < 4; ++kt)
            acc[nt] = __builtin_amdgcn_mfma_f32_16x16x32_bf16(a[kt], Wf[(nt * 4 + kt) * 64 + lane], acc[nt], 0, 0, 0);
    }

#pragma unroll
    for (int nt = 0; nt < 8; ++nt) {
        float b = Bias[nt * 16 + lr];
#pragma unroll
        for (int j = 0; j < 4; ++j) {
            long r = m0 + lg * 4 + j;
            if (r < nrows) Y[r * 128 + nt * 16 + lr] = f2bf(acc[nt][j] + b);
        }
    }
}

// ---------------- aggregation (MLP-widened): depth-2 load chain, width 16 ----------------

#define AGG_STEP(NR, U) { float nr_ = di * (NR); ax = fmaf(nr_, bflo(U), ax); ay = fmaf(nr_, bfhi(U), ay); }

template<int OUT_BF16>
__global__ __launch_bounds__(256) void k_agg(const unsigned* __restrict__ hu, const float* __restrict__ dinv,
                                             const int* __restrict__ cnt, const int* __restrict__ bucket,
                                             void* __restrict__ outv, int n, int do_relu) {
    int wid = threadIdx.x >> 6, lane = threadIdx.x & 63;
    int nd = blockIdx.x * 4 + wid;
    if (nd >= n) return;
    float di = dinv[nd];
    unsigned v = hu[(long)nd * 64 + lane];
    float ax = di * di * bflo(v);
    float ay = di * di * bfhi(v);
    int m = cnt[nd]; if (m > CAP) m = CAP;
    const int* bk = bucket + (long)nd * CAP;
    int j = 0;
    for (; j + 8 <= m; j += 8) {
        int4 i0 = *(const int4*)(bk + j);
        int4 i1 = *(const int4*)(bk + j + 4);
        float n0 = dinv[i0.x], n1 = dinv[i0.y], n2 = dinv[i0.z], n3 = dinv[i0.w];
        float n4 = dinv[i1.x], n5 = dinv[i1.y], n6 = dinv[i1.z], n7 = dinv[i1.w];
        unsigned u0 = hu[(long)i0.x * 64 + lane], u1 = hu[(long)i0.y * 64 + lane];
        unsigned u2 = hu[(long)i0.z * 64 + lane], u3 = hu[(long)i0.w * 64 + lane];
        unsigned u4 = hu[(long)i1.x * 64 + lane], u5 = hu[(long)i1.y * 64 + lane];
        unsigned u6 = hu[(long)i1.z * 64 + lane], u7 = hu[(long)i1.w * 64 + lane];
        AGG_STEP(n0, u0) AGG_STEP(n1, u1) AGG_STEP(n2, u2) AGG_STEP(n3, u3)
        AGG_STEP(n4, u4) AGG_STEP(n5, u5) AGG_STEP(n6, u6) AGG_STEP(n7, u7)
    }
    if (j + 4 <= m) {
        int4 i0 = *(const int4*)(bk + j);
        float n0 = dinv[i0.x], n1 = dinv[i0.y], n2 = dinv[i0.z], n3 = dinv[i0.w];
        unsigned u0 = hu[(long)i0.x * 64 + lane], u1 = hu[(long)i0.y * 64 + lane];
        unsigned u2 = hu[(long)i0.z * 64 + lane], u3 = hu[(long)i0.w * 64 + lane];
        AGG_STEP(n0, u0) AGG_STEP(n1, u1) AGG_STEP(n2, u2) AGG_STEP(n3, u3)
        j += 4;
    }
    for (; j < m; ++j) {
        int c = bk[j];
        float nr = dinv[c];
        unsigned u = hu[(long)c * 64 + lane];
        AGG_STEP(nr, u)
    }
    if (do_relu) { ax = fmaxf(ax, 0.f); ay = fmaxf(ay, 0.f); }
    if (OUT_BF16) {
        ((unsigned*)outv)[(long)nd * 64 + lane] = (unsigned)f2bf(ax) | ((unsigned)f2bf(ay) << 16);
    } else {
        float2 o; o.x = ax; o.y = ay;
        ((float2*)outv)[(long)nd * 64 + lane] = o;
    }
}

// ---------------- atomic-scatter fallback (bf16 h, fp32 g) ----------------

__global__ __launch_bounds__(256) void k_selfinit(const unsigned* __restrict__ hu, const float* __restrict__ dinv,
                                                  float* __restrict__ g, int n) {
    long i = (long)blockIdx.x * 256 + threadIdx.x;
    if (i >= (long)n * 64) return;
    int node = (int)(i >> 6);
    float d = dinv[node];
    unsigned u = hu[i];
    float2 o; o.x = d * d * bflo(u); o.y = d * d * bfhi(u);
    ((float2*)g)[i] = o;
}

__global__ __launch_bounds__(256) void k_scatter(const int* __restrict__ row, const int* __restrict__ col,
                                                 const float* __restrict__ dinv, const unsigned* __restrict__ hu,
                                                 float* __restrict__ g, int ne) {
    int e = blockIdx.x * 4 + (threadIdx.x >> 6);
    int lane = threadIdx.x & 63;
    if (e >= ne) return;
    int r = row[e], c = col[e];
    float nrm = dinv[r] * dinv[c];
    unsigned u = hu[(long)c * 64 + lane];
    atomicAdd(&g[(long)r * 128 + lane * 2], nrm * bflo(u));
    atomicAdd(&g[(long)r * 128 + lane * 2 + 1], nrm * bfhi(u));
}

__global__ __launch_bounds__(256) void k_reluf2bf(const float* __restrict__ g, unsigned* __restrict__ g16, long n2) {
    long i = (long)blockIdx.x * 256 + threadIdx.x;   // over n*64 pairs
    if (i >= n2) return;
    float2 v = ((const float2*)g)[i];
    g16[i] = (unsigned)f2bf(fmaxf(v.x, 0.f)) | ((unsigned)f2bf(fmaxf(v.y, 0.f)) << 16);
}

// ---------------- mean pool per graph (batch is sorted), two-stage ----------------

__global__ __launch_bounds__(256) void k_pool_partial(const float* __restrict__ g, const int* __restrict__ batch,
                                                      int n, float* __restrict__ partial, int* __restrict__ cntg) {
    int gid = blockIdx.x >> 3;
    int s   = blockIdx.x & 7;
    int t = threadIdx.x;
    int lo = 0, hi = n;
    while (lo < hi) { int m = (lo + hi) >> 1; if (batch[m] < gid) lo = m + 1; else hi = m; }
    int s0 = lo;
    hi = n;
    while (lo < hi) { int m = (lo + hi) >> 1; if (batch[m] < gid + 1) lo = m + 1; else hi = m; }
    int e0 = lo;
    if (s == 0 && t == 0) cntg[gid] = e0 - s0;

    int cq = t & 31, rl = t >> 5;
    const float4* g4 = (const float4*)g;
    float4 acc = make_float4(0.f, 0.f, 0.f, 0.f);
    for (int i = s0 + s * 8 + rl; i < e0; i += 64) {
        float4 v = g4[(long)i * 32 + cq];
        acc.x += v.x; acc.y += v.y; acc.z += v.z; acc.w += v.w;
    }
    __shared__ float4 red[256];
    red[t] = acc;
    __syncthreads();
    if (t < 32) {
        float4 a = red[t];
#pragma unroll
        for (int r = 1; r < 8; ++r) {
            float4 b = red[r * 32 + t];
            a.x += b.x; a.y += b.y; a.z += b.z; a.w += b.w;
        }
        ((float4*)partial)[(long)blockIdx.x * 32 + t] = a;
    }
}

__global__ __launch_bounds__(256) void k_pool_final(const float* __restrict__ partial, const int* __restrict__ cntg,
                                                    int ng, float* __restrict__ out) {
    int idx = blockIdx.x * 256 + threadIdx.x;
    if (idx >= ng * 128) return;
    int gid = idx >> 7, col = idx & 127;
    float a = 0.f;
#pragma unroll
    for (int s = 0; s < POOL_S; ++s) a += partial[(long)(gid * POOL_S + s) * 128 + col];
    out[idx] = a / fmaxf((float)cntg[gid], 1.0f);
}

// ---------------- host ----------------

extern "C" void kernel_launch(void* const* d_in, const int* in_sizes, int n_in,
                              void* d_out, int out_size, void* d_ws, size_t ws_size,
                              hipStream_t stream) {
    const float* x  = (const float*)d_in[0];
    const int* ei   = (const int*)d_in[1];
    const int* batch = (const int*)d_in[2];
    const float* W1 = (const float*)d_in[4];
    const float* b1 = (const float*)d_in[5];
    const float* W2 = (const float*)d_in[6];
    const float* b2 = (const float*)d_in[7];

    int N = in_sizes[0] / 128;
    int E = in_sizes[1] / 2;
    const int* row = ei;
    const int* col = ei + E;
    int G = out_size / 128;

    char* ws = (char*)d_ws;
    size_t off = 0;
    auto alloc = [&](size_t bytes) -> void* {
        void* p = ws + off;
        off += (bytes + 255) & ~(size_t)255;
        return p;
    };
    float* dinv = (float*)alloc((size_t)N * 4);
    int* cnt    = (int*)alloc((size_t)N * 4);
    unsigned short* h = (unsigned short*)alloc((size_t)N * 256);   // bf16 h (gemm out)
    float* g    = (float*)alloc((size_t)N * 512);                  // fp32 agg out (layer2) / bf16 (layer1)
    float* partial = (float*)alloc((size_t)G * POOL_S * 128 * 4);
    int* cntg   = (int*)alloc((size_t)G * 4);
    uint4* wp1  = (uint4*)alloc(32768);
    uint4* wp2  = (uint4*)alloc(32768);
    size_t bucket_bytes = (size_t)N * CAP * 4;
    bool use_bucket = (off + bucket_bytes) <= ws_size;
    int* bucket = use_bucket ? (int*)alloc(bucket_bytes) : nullptr;

    int nbN = (N + 255) / 256;
    int nbE = (E + 255) / 256;

    k_init<<<nbN, 256, 0, stream>>>(dinv, cnt, N);
    if (use_bucket)
        k_edge<<<nbE, 256, 0, stream>>>(row, col, dinv, cnt, bucket, E);
    else
        k_edge_deg<<<nbE, 256, 0, stream>>>(col, dinv, E);
    k_dinv<<<nbN, 256, 0, stream>>>(dinv, N);
    k_prepW<<<8, 256, 0, stream>>>(W1, wp1);
    k_prepW<<<8, 256, 0, stream>>>(W2, wp2);

    int gemm_blocks = (N + 63) / 64;
    int agg_blocks  = (N + 3) / 4;

    if (use_bucket) {
        // layer 1: gemm(fp32 in) -> h bf16; agg -> g bf16 (relu fused)
        k_gemm_mfma<0><<<gemm_blocks, 256, 0, stream>>>(x, (const float4*)wp1, b1, h, N);
        k_agg<1><<<agg_blocks, 256, 0, stream>>>((const unsigned*)h, dinv, cnt, bucket, g, N, 1);
        // layer 2: gemm(bf16 in) -> h bf16; agg -> g fp32
        k_gemm_mfma<1><<<gemm_blocks, 256, 0, stream>>>(g, (const float4*)wp2, b2, h, N);
        k_agg<0><<<agg_blocks, 256, 0, stream>>>((const unsigned*)h, dinv, cnt, bucket, g, N, 0);
    } else {
        unsigned* g16 = (unsigned*)h;  // careful: reuse pattern below keeps h live; use separate region
        // fallback keeps fp32 g; bf16 conversion for gemm2 input via k_reluf2bf into spare
        k_gemm_mfma<0><<<gemm_blocks, 256, 0, stream>>>(x, (const float4*)wp1, b1, h, N);
        k_selfinit<<<(int)(((long)N * 64 + 255) / 256), 256, 0, stream>>>((const unsigned*)h, dinv, g, N);
        k_scatter<<<(E + 3) / 4, 256, 0, stream>>>(row, col, dinv, (const unsigned*)h, g, E);
        k_reluf2bf<<<(int)(((long)N * 64 + 255) / 256), 256, 0, stream>>>(g, (unsigned*)h, (long)N * 64);
        k_gemm_mfma<1><<<gemm_blocks, 256, 0, stream>>>(h, (const float4*)wp2, b2, h, N);
        k_selfinit<<<(int)(((long)N * 64 + 255) / 256), 256, 0, stream>>>((const unsigned*)h, dinv, g, N);
        k_scatter<<<(E + 3) / 4, 256, 0, stream>>>(row, col, dinv, (const unsigned*)h, g, E);
    }

    // mean pool: two-stage
    k_pool_partial<<<G * POOL_S, 256, 0, stream>>>(g, batch, N, partial, cntg);
    k_pool_final<<<(G * 128 + 255) / 256, 256, 0, stream>>>(partial, cntg, G, (float*)d_out);
}

// Round 5
// 218.229 us; speedup vs baseline: 2.0207x; 1.0536x over previous
//
#include <hip/hip_runtime.h>

#define CAP 40
#define POOL_S 8

typedef __bf16 bf16x8 __attribute__((ext_vector_type(8)));
typedef float f32x4 __attribute__((ext_vector_type(4)));

__device__ __forceinline__ unsigned short f2bf(float f) {
    unsigned u = __float_as_uint(f);
    unsigned r = u + 0x7FFFu + ((u >> 16) & 1u);
    return (unsigned short)(r >> 16);
}
__device__ __forceinline__ float bflo(unsigned u) { return __uint_as_float(u << 16); }
__device__ __forceinline__ float bfhi(unsigned u) { return __uint_as_float(u & 0xFFFF0000u); }

// ---------------- W pre-pack (device fn): fp32 128x128 -> bf16 MFMA B-fragment t ----------------

__device__ __forceinline__ void prepW_one(const float* __restrict__ W, uint4* __restrict__ Wp, int t) {
    int slot = t >> 6, lane = t & 63;
    int nt = slot >> 2, kt = slot & 3;
    int kbase = kt * 32 + (lane >> 4) * 8;
    int colw = nt * 16 + (lane & 15);
    unsigned short e[8];
#pragma unroll
    for (int j = 0; j < 8; ++j) e[j] = f2bf(W[(kbase + j) * 128 + colw]);
    uint4 v;
    v.x = e[0] | ((unsigned)e[1] << 16);
    v.y = e[2] | ((unsigned)e[3] << 16);
    v.z = e[4] | ((unsigned)e[5] << 16);
    v.w = e[6] | ((unsigned)e[7] << 16);
    Wp[t] = v;
}

// prep: zero degi/cnt, pack both W matrices
__global__ __launch_bounds__(256) void k_prep(const float* __restrict__ W1, const float* __restrict__ W2,
                                              uint4* __restrict__ wp1, uint4* __restrict__ wp2,
                                              int* degi, int* cnt, int n) {
    int i = blockIdx.x * 256 + threadIdx.x;
    if (i < n) { degi[i] = 0; cnt[i] = 0; }
    if (i < 2048) prepW_one(W1, wp1, i);
    else if (i < 4096) prepW_one(W2, wp2, i - 2048);
}

__global__ __launch_bounds__(256) void k_dinv(const int* __restrict__ degi, float* __restrict__ dinv, int n) {
    int i = blockIdx.x * 256 + threadIdx.x;
    if (i < n) dinv[i] = rsqrtf((float)degi[i] + 1.0f);   // +1: self loop
}

// ---------------- GEMM block body (device fn): 64 rows x 128 cols per block ----------------

template<int IN_BF16>
__device__ __forceinline__ void gemm_block(const void* __restrict__ Xv,
        const float4* __restrict__ Wp, const float* __restrict__ Bias,
        unsigned short* __restrict__ Y, int nrows, int blk) {
    __shared__ float4 Wl[2048];   // 32 KB packed W fragments
    int t = threadIdx.x;
#pragma unroll
    for (int i = 0; i < 8; ++i) Wl[t + 256 * i] = Wp[t + 256 * i];
    __syncthreads();

    int wid = t >> 6, lane = t & 63;
    long m0 = ((long)blk * 4 + wid) * 16;
    if (m0 >= nrows) return;
    int lr = lane & 15, lg = lane >> 4;
    long mr = m0 + lr; if (mr > (long)nrows - 1) mr = nrows - 1;

    bf16x8 a[4];
    if (IN_BF16) {
        const unsigned short* xb = (const unsigned short*)Xv + mr * 128 + lg * 8;
#pragma unroll
        for (int kt = 0; kt < 4; ++kt) a[kt] = *(const bf16x8*)(xb + kt * 32);
    } else {
        const float* xrow = (const float*)Xv + mr * 128 + lg * 8;
#pragma unroll
        for (int kt = 0; kt < 4; ++kt) {
            float4 lo = *(const float4*)(xrow + kt * 32);
            float4 hi = *(const float4*)(xrow + kt * 32 + 4);
            bf16x8 v;
            v[0] = (__bf16)lo.x; v[1] = (__bf16)lo.y; v[2] = (__bf16)lo.z; v[3] = (__bf16)lo.w;
            v[4] = (__bf16)hi.x; v[5] = (__bf16)hi.y; v[6] = (__bf16)hi.z; v[7] = (__bf16)hi.w;
            a[kt] = v;
        }
    }

    const bf16x8* Wf = (const bf16x8*)Wl;
    f32x4 acc[8];
#pragma unroll
    for (int nt = 0; nt < 8; ++nt) acc[nt] = (f32x4)(0.0f);
#pragma unroll
    for (int nt = 0; nt < 8; ++nt) {
#pragma unroll
        for (int kt = 0; kt < 4; ++kt)
            acc[nt] = __builtin_amdgcn_mfma_f32_16x16x32_bf16(a[kt], Wf[(nt * 4 + kt) * 64 + lane], acc[nt], 0, 0, 0);
    }

#pragma unroll
    for (int nt = 0; nt < 8; ++nt) {
        float b = Bias[nt * 16 + lr];
#pragma unroll
        for (int j = 0; j < 4; ++j) {
            long r = m0 + lg * 4 + j;
            if (r < nrows) Y[r * 128 + nt * 16 + lr] = f2bf(acc[nt][j] + b);
        }
    }
}

// ---------------- fat kernel: gemm1 blocks + edge-pass blocks ----------------

__global__ __launch_bounds__(256) void k_gemm1_edge(const float* __restrict__ X,
        const float4* __restrict__ Wp, const float* __restrict__ Bias,
        unsigned short* __restrict__ Y, int nrows, int gemm_blocks,
        const int* __restrict__ row, const int* __restrict__ col,
        int* degi, int* cnt, int* bucket, int ne) {
    if ((int)blockIdx.x < gemm_blocks) {
        gemm_block<0>(X, Wp, Bias, Y, nrows, blockIdx.x);
        return;
    }
    long base = (((long)blockIdx.x - gemm_blocks) * 256 + threadIdx.x) * 4;
    if (base >= ne) return;
    int r0, r1, r2, r3, c0, c1, c2, c3;
    int k = (int)(ne - base); if (k > 4) k = 4;
    r0 = row[base]; c0 = col[base];
    r1 = k > 1 ? row[base + 1] : r0; c1 = k > 1 ? col[base + 1] : c0;
    r2 = k > 2 ? row[base + 2] : r0; c2 = k > 2 ? col[base + 2] : c0;
    r3 = k > 3 ? row[base + 3] : r0; c3 = k > 3 ? col[base + 3] : c0;
    // issue all deg atomics (fire-and-forget), then all cnt atomics, then stores
    atomicAdd(&degi[c0], 1);
    if (k > 1) atomicAdd(&degi[c1], 1);
    if (k > 2) atomicAdd(&degi[c2], 1);
    if (k > 3) atomicAdd(&degi[c3], 1);
    int p0 = atomicAdd(&cnt[r0], 1);
    int p1 = k > 1 ? atomicAdd(&cnt[r1], 1) : CAP;
    int p2 = k > 2 ? atomicAdd(&cnt[r2], 1) : CAP;
    int p3 = k > 3 ? atomicAdd(&cnt[r3], 1) : CAP;
    if (p0 < CAP) bucket[r0 * CAP + p0] = c0;
    if (p1 < CAP) bucket[r1 * CAP + p1] = c1;
    if (p2 < CAP) bucket[r2 * CAP + p2] = c2;
    if (p3 < CAP) bucket[r3 * CAP + p3] = c3;
}

// thin gemm wrapper (layer 2 / fallback)
template<int IN_BF16>
__global__ __launch_bounds__(256) void k_gemm_mfma(const void* __restrict__ Xv,
        const float4* __restrict__ Wp, const float* __restrict__ Bias,
        unsigned short* __restrict__ Y, int nrows) {
    gemm_block<IN_BF16>(Xv, Wp, Bias, Y, nrows, blockIdx.x);
}

// ---------------- aggregation (MLP-widened) ----------------

#define AGG_STEP(NR, U) { float nr_ = di * (NR); ax = fmaf(nr_, bflo(U), ax); ay = fmaf(nr_, bfhi(U), ay); }

template<int OUT_BF16>
__global__ __launch_bounds__(256) void k_agg(const unsigned* __restrict__ hu, const float* __restrict__ dinv,
                                             const int* __restrict__ cnt, const int* __restrict__ bucket,
                                             void* __restrict__ outv, int n, int do_relu) {
    int wid = threadIdx.x >> 6, lane = threadIdx.x & 63;
    int nd = blockIdx.x * 4 + wid;
    if (nd >= n) return;
    float di = dinv[nd];
    unsigned v = hu[(long)nd * 64 + lane];
    float ax = di * di * bflo(v);
    float ay = di * di * bfhi(v);
    int m = cnt[nd]; if (m > CAP) m = CAP;
    const int* bk = bucket + (long)nd * CAP;
    int j = 0;
    for (; j + 8 <= m; j += 8) {
        int4 i0 = *(const int4*)(bk + j);
        int4 i1 = *(const int4*)(bk + j + 4);
        float n0 = dinv[i0.x], n1 = dinv[i0.y], n2 = dinv[i0.z], n3 = dinv[i0.w];
        float n4 = dinv[i1.x], n5 = dinv[i1.y], n6 = dinv[i1.z], n7 = dinv[i1.w];
        unsigned u0 = hu[(long)i0.x * 64 + lane], u1 = hu[(long)i0.y * 64 + lane];
        unsigned u2 = hu[(long)i0.z * 64 + lane], u3 = hu[(long)i0.w * 64 + lane];
        unsigned u4 = hu[(long)i1.x * 64 + lane], u5 = hu[(long)i1.y * 64 + lane];
        unsigned u6 = hu[(long)i1.z * 64 + lane], u7 = hu[(long)i1.w * 64 + lane];
        AGG_STEP(n0, u0) AGG_STEP(n1, u1) AGG_STEP(n2, u2) AGG_STEP(n3, u3)
        AGG_STEP(n4, u4) AGG_STEP(n5, u5) AGG_STEP(n6, u6) AGG_STEP(n7, u7)
    }
    if (j + 4 <= m) {
        int4 i0 = *(const int4*)(bk + j);
        float n0 = dinv[i0.x], n1 = dinv[i0.y], n2 = dinv[i0.z], n3 = dinv[i0.w];
        unsigned u0 = hu[(long)i0.x * 64 + lane], u1 = hu[(long)i0.y * 64 + lane];
        unsigned u2 = hu[(long)i0.z * 64 + lane], u3 = hu[(long)i0.w * 64 + lane];
        AGG_STEP(n0, u0) AGG_STEP(n1, u1) AGG_STEP(n2, u2) AGG_STEP(n3, u3)
        j += 4;
    }
    for (; j < m; ++j) {
        int c = bk[j];
        float nr = dinv[c];
        unsigned u = hu[(long)c * 64 + lane];
        AGG_STEP(nr, u)
    }
    if (do_relu) { ax = fmaxf(ax, 0.f); ay = fmaxf(ay, 0.f); }
    if (OUT_BF16) {
        ((unsigned*)outv)[(long)nd * 64 + lane] = (unsigned)f2bf(ax) | ((unsigned)f2bf(ay) << 16);
    } else {
        float2 o; o.x = ax; o.y = ay;
        ((float2*)outv)[(long)nd * 64 + lane] = o;
    }
}

// ---------------- atomic-scatter fallback ----------------

__global__ __launch_bounds__(256) void k_edge_deg_i(const int* __restrict__ col, int* degi, int ne) {
    int e = blockIdx.x * 256 + threadIdx.x;
    if (e >= ne) return;
    atomicAdd(&degi[col[e]], 1);
}

__global__ __launch_bounds__(256) void k_selfinit(const unsigned* __restrict__ hu, const float* __restrict__ dinv,
                                                  float* __restrict__ g, int n) {
    long i = (long)blockIdx.x * 256 + threadIdx.x;
    if (i >= (long)n * 64) return;
    int node = (int)(i >> 6);
    float d = dinv[node];
    unsigned u = hu[i];
    float2 o; o.x = d * d * bflo(u); o.y = d * d * bfhi(u);
    ((float2*)g)[i] = o;
}

__global__ __launch_bounds__(256) void k_scatter(const int* __restrict__ row, const int* __restrict__ col,
                                                 const float* __restrict__ dinv, const unsigned* __restrict__ hu,
                                                 float* __restrict__ g, int ne) {
    int e = blockIdx.x * 4 + (threadIdx.x >> 6);
    int lane = threadIdx.x & 63;
    if (e >= ne) return;
    int r = row[e], c = col[e];
    float nrm = dinv[r] * dinv[c];
    unsigned u = hu[(long)c * 64 + lane];
    atomicAdd(&g[(long)r * 128 + lane * 2], nrm * bflo(u));
    atomicAdd(&g[(long)r * 128 + lane * 2 + 1], nrm * bfhi(u));
}

__global__ __launch_bounds__(256) void k_reluf2bf(const float* __restrict__ g, unsigned* __restrict__ g16, long n2) {
    long i = (long)blockIdx.x * 256 + threadIdx.x;
    if (i >= n2) return;
    float2 v = ((const float2*)g)[i];
    g16[i] = (unsigned)f2bf(fmaxf(v.x, 0.f)) | ((unsigned)f2bf(fmaxf(v.y, 0.f)) << 16);
}

// ---------------- mean pool (two-stage) ----------------

__global__ __launch_bounds__(256) void k_pool_partial(const float* __restrict__ g, const int* __restrict__ batch,
                                                      int n, float* __restrict__ partial, int* __restrict__ cntg) {
    int gid = blockIdx.x >> 3;
    int s   = blockIdx.x & 7;
    int t = threadIdx.x;
    int lo = 0, hi = n;
    while (lo < hi) { int m = (lo + hi) >> 1; if (batch[m] < gid) lo = m + 1; else hi = m; }
    int s0 = lo;
    hi = n;
    while (lo < hi) { int m = (lo + hi) >> 1; if (batch[m] < gid + 1) lo = m + 1; else hi = m; }
    int e0 = lo;
    if (s == 0 && t == 0) cntg[gid] = e0 - s0;

    int cq = t & 31, rl = t >> 5;
    const float4* g4 = (const float4*)g;
    float4 acc = make_float4(0.f, 0.f, 0.f, 0.f);
    for (int i = s0 + s * 8 + rl; i < e0; i += 64) {
        float4 v = g4[(long)i * 32 + cq];
        acc.x += v.x; acc.y += v.y; acc.z += v.z; acc.w += v.w;
    }
    __shared__ float4 red[256];
    red[t] = acc;
    __syncthreads();
    if (t < 32) {
        float4 a = red[t];
#pragma unroll
        for (int r = 1; r < 8; ++r) {
            float4 b = red[r * 32 + t];
            a.x += b.x; a.y += b.y; a.z += b.z; a.w += b.w;
        }
        ((float4*)partial)[(long)blockIdx.x * 32 + t] = a;
    }
}

__global__ __launch_bounds__(256) void k_pool_final(const float* __restrict__ partial, const int* __restrict__ cntg,
                                                    int ng, float* __restrict__ out) {
    int idx = blockIdx.x * 256 + threadIdx.x;
    if (idx >= ng * 128) return;
    int gid = idx >> 7, col = idx & 127;
    float a = 0.f;
#pragma unroll
    for (int s = 0; s < POOL_S; ++s) a += partial[(long)(gid * POOL_S + s) * 128 + col];
    out[idx] = a / fmaxf((float)cntg[gid], 1.0f);
}

// ---------------- host ----------------

extern "C" void kernel_launch(void* const* d_in, const int* in_sizes, int n_in,
                              void* d_out, int out_size, void* d_ws, size_t ws_size,
                              hipStream_t stream) {
    const float* x  = (const float*)d_in[0];
    const int* ei   = (const int*)d_in[1];
    const int* batch = (const int*)d_in[2];
    const float* W1 = (const float*)d_in[4];
    const float* b1 = (const float*)d_in[5];
    const float* W2 = (const float*)d_in[6];
    const float* b2 = (const float*)d_in[7];

    int N = in_sizes[0] / 128;
    int E = in_sizes[1] / 2;
    const int* row = ei;
    const int* col = ei + E;
    int G = out_size / 128;

    char* ws = (char*)d_ws;
    size_t off = 0;
    auto alloc = [&](size_t bytes) -> void* {
        void* p = ws + off;
        off += (bytes + 255) & ~(size_t)255;
        return p;
    };
    int* degi   = (int*)alloc((size_t)N * 4);
    float* dinv = (float*)alloc((size_t)N * 4);
    int* cnt    = (int*)alloc((size_t)N * 4);
    unsigned short* h = (unsigned short*)alloc((size_t)N * 256);   // bf16 h (gemm out)
    float* g    = (float*)alloc((size_t)N * 512);                  // agg out: bf16 (L1) / fp32 (L2)
    float* partial = (float*)alloc((size_t)G * POOL_S * 128 * 4);
    int* cntg   = (int*)alloc((size_t)G * 4);
    uint4* wp1  = (uint4*)alloc(32768);
    uint4* wp2  = (uint4*)alloc(32768);
    size_t bucket_bytes = (size_t)N * CAP * 4;
    bool use_bucket = (off + bucket_bytes) <= ws_size;
    int* bucket = use_bucket ? (int*)alloc(bucket_bytes) : nullptr;

    int nbN = (N + 255) / 256;
    int gemm_blocks = (N + 63) / 64;
    int agg_blocks  = (N + 3) / 4;
    int edge_blocks = (E + 1023) / 1024;

    k_prep<<<nbN, 256, 0, stream>>>(W1, W2, wp1, wp2, degi, cnt, N);

    if (use_bucket) {
        // gemm1 || edge pass (independent)
        k_gemm1_edge<<<gemm_blocks + edge_blocks, 256, 0, stream>>>(
            x, (const float4*)wp1, b1, h, N, gemm_blocks, row, col, degi, cnt, bucket, E);
        k_dinv<<<nbN, 256, 0, stream>>>(degi, dinv, N);
        k_agg<1><<<agg_blocks, 256, 0, stream>>>((const unsigned*)h, dinv, cnt, bucket, g, N, 1);
        k_gemm_mfma<1><<<gemm_blocks, 256, 0, stream>>>(g, (const float4*)wp2, b2, h, N);
        k_agg<0><<<agg_blocks, 256, 0, stream>>>((const unsigned*)h, dinv, cnt, bucket, g, N, 0);
    } else {
        k_edge_deg_i<<<(E + 255) / 256, 256, 0, stream>>>(col, degi, E);
        k_dinv<<<nbN, 256, 0, stream>>>(degi, dinv, N);
        k_gemm_mfma<0><<<gemm_blocks, 256, 0, stream>>>(x, (const float4*)wp1, b1, h, N);
        k_selfinit<<<(int)(((long)N * 64 + 255) / 256), 256, 0, stream>>>((const unsigned*)h, dinv, g, N);
        k_scatter<<<(E + 3) / 4, 256, 0, stream>>>(row, col, dinv, (const unsigned*)h, g, E);
        k_reluf2bf<<<(int)(((long)N * 64 + 255) / 256), 256, 0, stream>>>(g, (unsigned*)h, (long)N * 64);
        k_gemm_mfma<1><<<gemm_blocks, 256, 0, stream>>>(h, (const float4*)wp2, b2, h, N);
        k_selfinit<<<(int)(((long)N * 64 + 255) / 256), 256, 0, stream>>>((const unsigned*)h, dinv, g, N);
        k_scatter<<<(E + 3) / 4, 256, 0, stream>>>(row, col, dinv, (const unsigned*)h, g, E);
    }

    // mean pool: two-stage
    k_pool_partial<<<G * POOL_S, 256, 0, stream>>>(g, batch, N, partial, cntg);
    k_pool_final<<<(G * 128 + 255) / 256, 256, 0, stream>>>(partial, cntg, G, (float*)d_out);
}

// Round 6
// 217.031 us; speedup vs baseline: 2.0318x; 1.0055x over previous
//
#include <hip/hip_runtime.h>

#define CAP 40
#define POOL_S 8

typedef __bf16 bf16x8 __attribute__((ext_vector_type(8)));
typedef float f32x4 __attribute__((ext_vector_type(4)));

__device__ __forceinline__ unsigned short f2bf(float f) {
    unsigned u = __float_as_uint(f);
    unsigned r = u + 0x7FFFu + ((u >> 16) & 1u);
    return (unsigned short)(r >> 16);
}
__device__ __forceinline__ float bflo(unsigned u) { return __uint_as_float(u << 16); }
__device__ __forceinline__ float bfhi(unsigned u) { return __uint_as_float(u & 0xFFFF0000u); }

// ---------------- W pre-pack (device fn): fp32 128x128 -> bf16 MFMA B-fragment t ----------------

__device__ __forceinline__ void prepW_one(const float* __restrict__ W, uint4* __restrict__ Wp, int t) {
    int slot = t >> 6, lane = t & 63;
    int nt = slot >> 2, kt = slot & 3;
    int kbase = kt * 32 + (lane >> 4) * 8;
    int colw = nt * 16 + (lane & 15);
    unsigned short e[8];
#pragma unroll
    for (int j = 0; j < 8; ++j) e[j] = f2bf(W[(kbase + j) * 128 + colw]);
    uint4 v;
    v.x = e[0] | ((unsigned)e[1] << 16);
    v.y = e[2] | ((unsigned)e[3] << 16);
    v.z = e[4] | ((unsigned)e[5] << 16);
    v.w = e[6] | ((unsigned)e[7] << 16);
    Wp[t] = v;
}

__global__ __launch_bounds__(256) void k_prep(const float* __restrict__ W1, const float* __restrict__ W2,
                                              uint4* __restrict__ wp1, uint4* __restrict__ wp2,
                                              int* degi, int* cnt, int n) {
    int i = blockIdx.x * 256 + threadIdx.x;
    if (i < n) { degi[i] = 0; cnt[i] = 0; }
    if (i < 2048) prepW_one(W1, wp1, i);
    else if (i < 4096) prepW_one(W2, wp2, i - 2048);
}

__global__ __launch_bounds__(256) void k_dinv(const int* __restrict__ degi, float* __restrict__ dinv, int n) {
    int i = blockIdx.x * 256 + threadIdx.x;
    if (i < n) dinv[i] = rsqrtf((float)degi[i] + 1.0f);   // +1: self loop
}

// ---------------- GEMM block body: 64 rows x 128 cols per block ----------------

template<int IN_BF16>
__device__ __forceinline__ void gemm_block(const void* __restrict__ Xv,
        const float4* __restrict__ Wp, const float* __restrict__ Bias,
        unsigned short* __restrict__ Y, int nrows, int blk) {
    __shared__ float4 Wl[2048];   // 32 KB packed W fragments
    int t = threadIdx.x;
#pragma unroll
    for (int i = 0; i < 8; ++i) Wl[t + 256 * i] = Wp[t + 256 * i];
    __syncthreads();

    int wid = t >> 6, lane = t & 63;
    long m0 = ((long)blk * 4 + wid) * 16;
    if (m0 >= nrows) return;
    int lr = lane & 15, lg = lane >> 4;
    long mr = m0 + lr; if (mr > (long)nrows - 1) mr = nrows - 1;

    bf16x8 a[4];
    if (IN_BF16) {
        const unsigned short* xb = (const unsigned short*)Xv + mr * 128 + lg * 8;
#pragma unroll
        for (int kt = 0; kt < 4; ++kt) a[kt] = *(const bf16x8*)(xb + kt * 32);
    } else {
        const float* xrow = (const float*)Xv + mr * 128 + lg * 8;
#pragma unroll
        for (int kt = 0; kt < 4; ++kt) {
            float4 lo = *(const float4*)(xrow + kt * 32);
            float4 hi = *(const float4*)(xrow + kt * 32 + 4);
            bf16x8 v;
            v[0] = (__bf16)lo.x; v[1] = (__bf16)lo.y; v[2] = (__bf16)lo.z; v[3] = (__bf16)lo.w;
            v[4] = (__bf16)hi.x; v[5] = (__bf16)hi.y; v[6] = (__bf16)hi.z; v[7] = (__bf16)hi.w;
            a[kt] = v;
        }
    }

    const bf16x8* Wf = (const bf16x8*)Wl;
    f32x4 acc[8];
#pragma unroll
    for (int nt = 0; nt < 8; ++nt) acc[nt] = (f32x4)(0.0f);
#pragma unroll
    for (int nt = 0; nt < 8; ++nt) {
#pragma unroll
        for (int kt = 0; kt < 4; ++kt)
            acc[nt] = __builtin_amdgcn_mfma_f32_16x16x32_bf16(a[kt], Wf[(nt * 4 + kt) * 64 + lane], acc[nt], 0, 0, 0);
    }

#pragma unroll
    for (int nt = 0; nt < 8; ++nt) {
        float b = Bias[nt * 16 + lr];
#pragma unroll
        for (int j = 0; j < 4; ++j) {
            long r = m0 + lg * 4 + j;
            if (r < nrows) Y[r * 128 + nt * 16 + lr] = f2bf(acc[nt][j] + b);
        }
    }
}

// ---------------- fat kernel: EDGE blocks first (long pole), gemm1 blocks backfill ----------------

__global__ __launch_bounds__(256) void k_edge_gemm1(const float* __restrict__ X,
        const float4* __restrict__ Wp, const float* __restrict__ Bias,
        unsigned short* __restrict__ Y, int nrows, int edge_blocks,
        const int* __restrict__ row, const int* __restrict__ col,
        int* degi, int* cnt, int* bucket, int ne) {
    if ((int)blockIdx.x >= edge_blocks) {
        gemm_block<0>(X, Wp, Bias, Y, nrows, blockIdx.x - edge_blocks);
        return;
    }
    long base = ((long)blockIdx.x * 256 + threadIdx.x) * 4;
    if (base >= ne) return;
    int r0, r1, r2, r3, c0, c1, c2, c3;
    int k = (int)(ne - base); if (k > 4) k = 4;
    r0 = row[base]; c0 = col[base];
    r1 = k > 1 ? row[base + 1] : r0; c1 = k > 1 ? col[base + 1] : c0;
    r2 = k > 2 ? row[base + 2] : r0; c2 = k > 2 ? col[base + 2] : c0;
    r3 = k > 3 ? row[base + 3] : r0; c3 = k > 3 ? col[base + 3] : c0;
    atomicAdd(&degi[c0], 1);
    if (k > 1) atomicAdd(&degi[c1], 1);
    if (k > 2) atomicAdd(&degi[c2], 1);
    if (k > 3) atomicAdd(&degi[c3], 1);
    int p0 = atomicAdd(&cnt[r0], 1);
    int p1 = k > 1 ? atomicAdd(&cnt[r1], 1) : CAP;
    int p2 = k > 2 ? atomicAdd(&cnt[r2], 1) : CAP;
    int p3 = k > 3 ? atomicAdd(&cnt[r3], 1) : CAP;
    if (p0 < CAP) bucket[r0 * CAP + p0] = c0;
    if (p1 < CAP) bucket[r1 * CAP + p1] = c1;
    if (p2 < CAP) bucket[r2 * CAP + p2] = c2;
    if (p3 < CAP) bucket[r3 * CAP + p3] = c3;
}

template<int IN_BF16>
__global__ __launch_bounds__(256) void k_gemm_mfma(const void* __restrict__ Xv,
        const float4* __restrict__ Wp, const float* __restrict__ Bias,
        unsigned short* __restrict__ Y, int nrows) {
    gemm_block<IN_BF16>(Xv, Wp, Bias, Y, nrows, blockIdx.x);
}

// ---------------- aggregation (MLP-widened) ----------------

#define AGG_STEP(NR, U) { float nr_ = di * (NR); ax = fmaf(nr_, bflo(U), ax); ay = fmaf(nr_, bfhi(U), ay); }

template<int OUT_BF16>
__global__ __launch_bounds__(256) void k_agg(const unsigned* __restrict__ hu, const float* __restrict__ dinv,
                                             const int* __restrict__ cnt, const int* __restrict__ bucket,
                                             void* __restrict__ outv, int n, int do_relu) {
    int wid = threadIdx.x >> 6, lane = threadIdx.x & 63;
    int nd = blockIdx.x * 4 + wid;
    if (nd >= n) return;
    float di = dinv[nd];
    unsigned v = hu[(long)nd * 64 + lane];
    float ax = di * di * bflo(v);
    float ay = di * di * bfhi(v);
    int m = cnt[nd]; if (m > CAP) m = CAP;
    const int* bk = bucket + (long)nd * CAP;
    int j = 0;
    for (; j + 8 <= m; j += 8) {
        int4 i0 = *(const int4*)(bk + j);
        int4 i1 = *(const int4*)(bk + j + 4);
        float n0 = dinv[i0.x], n1 = dinv[i0.y], n2 = dinv[i0.z], n3 = dinv[i0.w];
        float n4 = dinv[i1.x], n5 = dinv[i1.y], n6 = dinv[i1.z], n7 = dinv[i1.w];
        unsigned u0 = hu[(long)i0.x * 64 + lane], u1 = hu[(long)i0.y * 64 + lane];
        unsigned u2 = hu[(long)i0.z * 64 + lane], u3 = hu[(long)i0.w * 64 + lane];
        unsigned u4 = hu[(long)i1.x * 64 + lane], u5 = hu[(long)i1.y * 64 + lane];
        unsigned u6 = hu[(long)i1.z * 64 + lane], u7 = hu[(long)i1.w * 64 + lane];
        AGG_STEP(n0, u0) AGG_STEP(n1, u1) AGG_STEP(n2, u2) AGG_STEP(n3, u3)
        AGG_STEP(n4, u4) AGG_STEP(n5, u5) AGG_STEP(n6, u6) AGG_STEP(n7, u7)
    }
    if (j + 4 <= m) {
        int4 i0 = *(const int4*)(bk + j);
        float n0 = dinv[i0.x], n1 = dinv[i0.y], n2 = dinv[i0.z], n3 = dinv[i0.w];
        unsigned u0 = hu[(long)i0.x * 64 + lane], u1 = hu[(long)i0.y * 64 + lane];
        unsigned u2 = hu[(long)i0.z * 64 + lane], u3 = hu[(long)i0.w * 64 + lane];
        AGG_STEP(n0, u0) AGG_STEP(n1, u1) AGG_STEP(n2, u2) AGG_STEP(n3, u3)
        j += 4;
    }
    for (; j < m; ++j) {
        int c = bk[j];
        float nr = dinv[c];
        unsigned u = hu[(long)c * 64 + lane];
        AGG_STEP(nr, u)
    }
    if (do_relu) { ax = fmaxf(ax, 0.f); ay = fmaxf(ay, 0.f); }
    if (OUT_BF16) {
        ((unsigned*)outv)[(long)nd * 64 + lane] = (unsigned)f2bf(ax) | ((unsigned)f2bf(ay) << 16);
    } else {
        float2 o; o.x = ax; o.y = ay;
        ((float2*)outv)[(long)nd * 64 + lane] = o;
    }
}

// ---------------- atomic-scatter fallback ----------------

__global__ __launch_bounds__(256) void k_edge_deg_i(const int* __restrict__ col, int* degi, int ne) {
    int e = blockIdx.x * 256 + threadIdx.x;
    if (e >= ne) return;
    atomicAdd(&degi[col[e]], 1);
}

__global__ __launch_bounds__(256) void k_selfinit(const unsigned* __restrict__ hu, const float* __restrict__ dinv,
                                                  float* __restrict__ g, int n) {
    long i = (long)blockIdx.x * 256 + threadIdx.x;
    if (i >= (long)n * 64) return;
    int node = (int)(i >> 6);
    float d = dinv[node];
    unsigned u = hu[i];
    float2 o; o.x = d * d * bflo(u); o.y = d * d * bfhi(u);
    ((float2*)g)[i] = o;
}

__global__ __launch_bounds__(256) void k_scatter(const int* __restrict__ row, const int* __restrict__ col,
                                                 const float* __restrict__ dinv, const unsigned* __restrict__ hu,
                                                 float* __restrict__ g, int ne) {
    int e = blockIdx.x * 4 + (threadIdx.x >> 6);
    int lane = threadIdx.x & 63;
    if (e >= ne) return;
    int r = row[e], c = col[e];
    float nrm = dinv[r] * dinv[c];
    unsigned u = hu[(long)c * 64 + lane];
    atomicAdd(&g[(long)r * 128 + lane * 2], nrm * bflo(u));
    atomicAdd(&g[(long)r * 128 + lane * 2 + 1], nrm * bfhi(u));
}

__global__ __launch_bounds__(256) void k_reluf2bf(const float* __restrict__ g, unsigned* __restrict__ g16, long n2) {
    long i = (long)blockIdx.x * 256 + threadIdx.x;
    if (i >= n2) return;
    float2 v = ((const float2*)g)[i];
    g16[i] = (unsigned)f2bf(fmaxf(v.x, 0.f)) | ((unsigned)f2bf(fmaxf(v.y, 0.f)) << 16);
}

__global__ __launch_bounds__(256) void k_f32tobf(const float* __restrict__ g, unsigned* __restrict__ g16, long n2) {
    long i = (long)blockIdx.x * 256 + threadIdx.x;
    if (i >= n2) return;
    float2 v = ((const float2*)g)[i];
    g16[i] = (unsigned)f2bf(v.x) | ((unsigned)f2bf(v.y) << 16);
}

// ---------------- mean pool (two-stage, bf16 input) ----------------
// Stage A: block = 4 row-waves; each wave reads one full 256B bf16 row per iter.
__global__ __launch_bounds__(256) void k_pool_partial_bf16(const unsigned* __restrict__ g16,
                                                           const int* __restrict__ batch,
                                                           int n, float* __restrict__ partial, int* __restrict__ cntg) {
    int gid = blockIdx.x >> 3;
    int s   = blockIdx.x & 7;
    int t = threadIdx.x;
    int lo = 0, hi = n;
    while (lo < hi) { int m = (lo + hi) >> 1; if (batch[m] < gid) lo = m + 1; else hi = m; }
    int s0 = lo;
    hi = n;
    while (lo < hi) { int m = (lo + hi) >> 1; if (batch[m] < gid + 1) lo = m + 1; else hi = m; }
    int e0 = lo;
    if (s == 0 && t == 0) cntg[gid] = e0 - s0;

    int lane = t & 63, wid = t >> 6;
    float ax = 0.f, ay = 0.f;
    for (int i = s0 + s * 4 + wid; i < e0; i += 32) {
        unsigned u = g16[(long)i * 64 + lane];
        ax += bflo(u); ay += bfhi(u);
    }
    __shared__ float2 red[256];
    red[t] = make_float2(ax, ay);
    __syncthreads();
    if (t < 64) {
        float2 a = red[t];
#pragma unroll
        for (int r = 1; r < 4; ++r) {
            float2 b = red[r * 64 + t];
            a.x += b.x; a.y += b.y;
        }
        ((float2*)partial)[(long)blockIdx.x * 64 + t] = a;
    }
}

__global__ __launch_bounds__(256) void k_pool_final(const float* __restrict__ partial, const int* __restrict__ cntg,
                                                    int ng, float* __restrict__ out) {
    int idx = blockIdx.x * 256 + threadIdx.x;
    if (idx >= ng * 128) return;
    int gid = idx >> 7, col = idx & 127;
    float a = 0.f;
#pragma unroll
    for (int s = 0; s < POOL_S; ++s) a += partial[(long)(gid * POOL_S + s) * 128 + col];
    out[idx] = a / fmaxf((float)cntg[gid], 1.0f);
}

// ---------------- host ----------------

extern "C" void kernel_launch(void* const* d_in, const int* in_sizes, int n_in,
                              void* d_out, int out_size, void* d_ws, size_t ws_size,
                              hipStream_t stream) {
    const float* x  = (const float*)d_in[0];
    const int* ei   = (const int*)d_in[1];
    const int* batch = (const int*)d_in[2];
    const float* W1 = (const float*)d_in[4];
    const float* b1 = (const float*)d_in[5];
    const float* W2 = (const float*)d_in[6];
    const float* b2 = (const float*)d_in[7];

    int N = in_sizes[0] / 128;
    int E = in_sizes[1] / 2;
    const int* row = ei;
    const int* col = ei + E;
    int G = out_size / 128;

    char* ws = (char*)d_ws;
    size_t off = 0;
    auto alloc = [&](size_t bytes) -> void* {
        void* p = ws + off;
        off += (bytes + 255) & ~(size_t)255;
        return p;
    };
    int* degi   = (int*)alloc((size_t)N * 4);
    float* dinv = (float*)alloc((size_t)N * 4);
    int* cnt    = (int*)alloc((size_t)N * 4);
    unsigned short* h = (unsigned short*)alloc((size_t)N * 256);   // bf16 h (gemm out)
    float* g    = (float*)alloc((size_t)N * 512);                  // agg out (bf16 both layers; fp32 in fallback)
    float* partial = (float*)alloc((size_t)G * POOL_S * 128 * 4);
    int* cntg   = (int*)alloc((size_t)G * 4);
    uint4* wp1  = (uint4*)alloc(32768);
    uint4* wp2  = (uint4*)alloc(32768);
    size_t bucket_bytes = (size_t)N * CAP * 4;
    bool use_bucket = (off + bucket_bytes) <= ws_size;
    int* bucket = use_bucket ? (int*)alloc(bucket_bytes) : nullptr;

    int nbN = (N + 255) / 256;
    int gemm_blocks = (N + 63) / 64;
    int agg_blocks  = (N + 3) / 4;
    int edge_blocks = (E + 1023) / 1024;

    k_prep<<<nbN, 256, 0, stream>>>(W1, W2, wp1, wp2, degi, cnt, N);

    if (use_bucket) {
        // edge pass (long pole, blocks first) || gemm1 (backfills)
        k_edge_gemm1<<<edge_blocks + gemm_blocks, 256, 0, stream>>>(
            x, (const float4*)wp1, b1, h, N, edge_blocks, row, col, degi, cnt, bucket, E);
        k_dinv<<<nbN, 256, 0, stream>>>(degi, dinv, N);
        k_agg<1><<<agg_blocks, 256, 0, stream>>>((const unsigned*)h, dinv, cnt, bucket, g, N, 1);
        k_gemm_mfma<1><<<gemm_blocks, 256, 0, stream>>>(g, (const float4*)wp2, b2, h, N);
        k_agg<1><<<agg_blocks, 256, 0, stream>>>((const unsigned*)h, dinv, cnt, bucket, g, N, 0);
        k_pool_partial_bf16<<<G * POOL_S, 256, 0, stream>>>((const unsigned*)g, batch, N, partial, cntg);
    } else {
        k_edge_deg_i<<<(E + 255) / 256, 256, 0, stream>>>(col, degi, E);
        k_dinv<<<nbN, 256, 0, stream>>>(degi, dinv, N);
        k_gemm_mfma<0><<<gemm_blocks, 256, 0, stream>>>(x, (const float4*)wp1, b1, h, N);
        k_selfinit<<<(int)(((long)N * 64 + 255) / 256), 256, 0, stream>>>((const unsigned*)h, dinv, g, N);
        k_scatter<<<(E + 3) / 4, 256, 0, stream>>>(row, col, dinv, (const unsigned*)h, g, E);
        k_reluf2bf<<<(int)(((long)N * 64 + 255) / 256), 256, 0, stream>>>(g, (unsigned*)h, (long)N * 64);
        k_gemm_mfma<1><<<gemm_blocks, 256, 0, stream>>>(h, (const float4*)wp2, b2, h, N);
        k_selfinit<<<(int)(((long)N * 64 + 255) / 256), 256, 0, stream>>>((const unsigned*)h, dinv, g, N);
        k_scatter<<<(E + 3) / 4, 256, 0, stream>>>(row, col, dinv, (const unsigned*)h, g, E);
        k_f32tobf<<<(int)(((long)N * 64 + 255) / 256), 256, 0, stream>>>(g, (unsigned*)g, (long)N * 64);
        k_pool_partial_bf16<<<G * POOL_S, 256, 0, stream>>>((const unsigned*)g, batch, N, partial, cntg);
    }

    // final mean
    k_pool_final<<<(G * 128 + 255) / 256, 256, 0, stream>>>(partial, cntg, G, (float*)d_out);
}

// Round 7
// 199.586 us; speedup vs baseline: 2.2094x; 1.0874x over previous
//
#include <hip/hip_runtime.h>

#define CAP 40
#define POOL_S 8

typedef __bf16 bf16x8 __attribute__((ext_vector_type(8)));
typedef float f32x4 __attribute__((ext_vector_type(4)));

__device__ __forceinline__ unsigned short f2bf(float f) {
    unsigned u = __float_as_uint(f);
    unsigned r = u + 0x7FFFu + ((u >> 16) & 1u);
    return (unsigned short)(r >> 16);
}
__device__ __forceinline__ float bflo(unsigned u) { return __uint_as_float(u << 16); }
__device__ __forceinline__ float bfhi(unsigned u) { return __uint_as_float(u & 0xFFFF0000u); }

// ---------------- W pre-pack (device fn): fp32 128x128 -> bf16 MFMA B-fragment t ----------------

__device__ __forceinline__ void prepW_one(const float* __restrict__ W, uint4* __restrict__ Wp, int t) {
    int slot = t >> 6, lane = t & 63;
    int nt = slot >> 2, kt = slot & 3;
    int kbase = kt * 32 + (lane >> 4) * 8;
    int colw = nt * 16 + (lane & 15);
    unsigned short e[8];
#pragma unroll
    for (int j = 0; j < 8; ++j) e[j] = f2bf(W[(kbase + j) * 128 + colw]);
    uint4 v;
    v.x = e[0] | ((unsigned)e[1] << 16);
    v.y = e[2] | ((unsigned)e[3] << 16);
    v.z = e[4] | ((unsigned)e[5] << 16);
    v.w = e[6] | ((unsigned)e[7] << 16);
    Wp[t] = v;
}

__global__ __launch_bounds__(256) void k_prep(const float* __restrict__ W1, const float* __restrict__ W2,
                                              uint4* __restrict__ wp1, uint4* __restrict__ wp2,
                                              int* degi, int* cnt, int n) {
    int i = blockIdx.x * 256 + threadIdx.x;
    if (i < n) { degi[i] = 0; cnt[i] = 0; }
    if (i < 2048) prepW_one(W1, wp1, i);
    else if (i < 4096) prepW_one(W2, wp2, i - 2048);
}

__global__ __launch_bounds__(256) void k_dinv(const int* __restrict__ degi, float* __restrict__ dinv, int n) {
    int i = blockIdx.x * 256 + threadIdx.x;
    if (i < n) dinv[i] = rsqrtf((float)degi[i] + 1.0f);   // +1: self loop
}

// ---------------- GEMM block body: 64 rows x 128 cols per block ----------------

template<int IN_BF16>
__device__ __forceinline__ void gemm_block(const void* __restrict__ Xv,
        const float4* __restrict__ Wp, const float* __restrict__ Bias,
        unsigned short* __restrict__ Y, int nrows, int blk) {
    __shared__ float4 Wl[2048];   // 32 KB packed W fragments
    int t = threadIdx.x;
#pragma unroll
    for (int i = 0; i < 8; ++i) Wl[t + 256 * i] = Wp[t + 256 * i];
    __syncthreads();

    int wid = t >> 6, lane = t & 63;
    long m0 = ((long)blk * 4 + wid) * 16;
    if (m0 >= nrows) return;
    int lr = lane & 15, lg = lane >> 4;
    long mr = m0 + lr; if (mr > (long)nrows - 1) mr = nrows - 1;

    bf16x8 a[4];
    if (IN_BF16) {
        const unsigned short* xb = (const unsigned short*)Xv + mr * 128 + lg * 8;
#pragma unroll
        for (int kt = 0; kt < 4; ++kt) a[kt] = *(const bf16x8*)(xb + kt * 32);
    } else {
        const float* xrow = (const float*)Xv + mr * 128 + lg * 8;
#pragma unroll
        for (int kt = 0; kt < 4; ++kt) {
            float4 lo = *(const float4*)(xrow + kt * 32);
            float4 hi = *(const float4*)(xrow + kt * 32 + 4);
            bf16x8 v;
            v[0] = (__bf16)lo.x; v[1] = (__bf16)lo.y; v[2] = (__bf16)lo.z; v[3] = (__bf16)lo.w;
            v[4] = (__bf16)hi.x; v[5] = (__bf16)hi.y; v[6] = (__bf16)hi.z; v[7] = (__bf16)hi.w;
            a[kt] = v;
        }
    }

    const bf16x8* Wf = (const bf16x8*)Wl;
    f32x4 acc[8];
#pragma unroll
    for (int nt = 0; nt < 8; ++nt) acc[nt] = (f32x4)(0.0f);
#pragma unroll
    for (int nt = 0; nt < 8; ++nt) {
#pragma unroll
        for (int kt = 0; kt < 4; ++kt)
            acc[nt] = __builtin_amdgcn_mfma_f32_16x16x32_bf16(a[kt], Wf[(nt * 4 + kt) * 64 + lane], acc[nt], 0, 0, 0);
    }

#pragma unroll
    for (int nt = 0; nt < 8; ++nt) {
        float b = Bias[nt * 16 + lr];
#pragma unroll
        for (int j = 0; j < 4; ++j) {
            long r = m0 + lg * 4 + j;
            if (r < nrows) Y[r * 128 + nt * 16 + lr] = f2bf(acc[nt][j] + b);
        }
    }
}

// ---------------- fat kernel: EDGE blocks first, gemm1 blocks backfill ----------------
// bucket is TRANSPOSED: bucket[pos * n + r] — dense per-pos 400KB windows.

__global__ __launch_bounds__(256) void k_edge_gemm1(const float* __restrict__ X,
        const float4* __restrict__ Wp, const float* __restrict__ Bias,
        unsigned short* __restrict__ Y, int nrows, int edge_blocks,
        const int* __restrict__ row, const int* __restrict__ col,
        int* degi, int* cnt, int* bucket, int ne) {
    if ((int)blockIdx.x >= edge_blocks) {
        gemm_block<0>(X, Wp, Bias, Y, nrows, blockIdx.x - edge_blocks);
        return;
    }
    int nn = nrows;
    long base = ((long)blockIdx.x * 256 + threadIdx.x) * 4;
    if (base >= ne) return;
    int r0, r1, r2, r3, c0, c1, c2, c3;
    int k = (int)(ne - base); if (k > 4) k = 4;
    r0 = row[base]; c0 = col[base];
    r1 = k > 1 ? row[base + 1] : r0; c1 = k > 1 ? col[base + 1] : c0;
    r2 = k > 2 ? row[base + 2] : r0; c2 = k > 2 ? col[base + 2] : c0;
    r3 = k > 3 ? row[base + 3] : r0; c3 = k > 3 ? col[base + 3] : c0;
    atomicAdd(&degi[c0], 1);
    if (k > 1) atomicAdd(&degi[c1], 1);
    if (k > 2) atomicAdd(&degi[c2], 1);
    if (k > 3) atomicAdd(&degi[c3], 1);
    int p0 = atomicAdd(&cnt[r0], 1);
    int p1 = k > 1 ? atomicAdd(&cnt[r1], 1) : CAP;
    int p2 = k > 2 ? atomicAdd(&cnt[r2], 1) : CAP;
    int p3 = k > 3 ? atomicAdd(&cnt[r3], 1) : CAP;
    if (p0 < CAP) bucket[p0 * nn + r0] = c0;
    if (p1 < CAP) bucket[p1 * nn + r1] = c1;
    if (p2 < CAP) bucket[p2 * nn + r2] = c2;
    if (p3 < CAP) bucket[p3 * nn + r3] = c3;
}

template<int IN_BF16>
__global__ __launch_bounds__(256) void k_gemm_mfma(const void* __restrict__ Xv,
        const float4* __restrict__ Wp, const float* __restrict__ Bias,
        unsigned short* __restrict__ Y, int nrows) {
    gemm_block<IN_BF16>(Xv, Wp, Bias, Y, nrows, blockIdx.x);
}

// ---------------- aggregation (MLP-widened, transposed bucket) ----------------

#define AGG_STEP(NR, U) { float nr_ = di * (NR); ax = fmaf(nr_, bflo(U), ax); ay = fmaf(nr_, bfhi(U), ay); }

template<int OUT_BF16>
__global__ __launch_bounds__(256) void k_agg(const unsigned* __restrict__ hu, const float* __restrict__ dinv,
                                             const int* __restrict__ cnt, const int* __restrict__ bucket,
                                             void* __restrict__ outv, int n, int do_relu) {
    int wid = threadIdx.x >> 6, lane = threadIdx.x & 63;
    int nd = blockIdx.x * 4 + wid;
    if (nd >= n) return;
    float di = dinv[nd];
    unsigned v = hu[(long)nd * 64 + lane];
    float ax = di * di * bflo(v);
    float ay = di * di * bfhi(v);
    int m = cnt[nd]; if (m > CAP) m = CAP;
    int j = 0;
    for (; j + 8 <= m; j += 8) {
        int c0 = bucket[(j + 0) * n + nd], c1 = bucket[(j + 1) * n + nd];
        int c2 = bucket[(j + 2) * n + nd], c3 = bucket[(j + 3) * n + nd];
        int c4 = bucket[(j + 4) * n + nd], c5 = bucket[(j + 5) * n + nd];
        int c6 = bucket[(j + 6) * n + nd], c7 = bucket[(j + 7) * n + nd];
        float n0 = dinv[c0], n1 = dinv[c1], n2 = dinv[c2], n3 = dinv[c3];
        float n4 = dinv[c4], n5 = dinv[c5], n6 = dinv[c6], n7 = dinv[c7];
        unsigned u0 = hu[(long)c0 * 64 + lane], u1 = hu[(long)c1 * 64 + lane];
        unsigned u2 = hu[(long)c2 * 64 + lane], u3 = hu[(long)c3 * 64 + lane];
        unsigned u4 = hu[(long)c4 * 64 + lane], u5 = hu[(long)c5 * 64 + lane];
        unsigned u6 = hu[(long)c6 * 64 + lane], u7 = hu[(long)c7 * 64 + lane];
        AGG_STEP(n0, u0) AGG_STEP(n1, u1) AGG_STEP(n2, u2) AGG_STEP(n3, u3)
        AGG_STEP(n4, u4) AGG_STEP(n5, u5) AGG_STEP(n6, u6) AGG_STEP(n7, u7)
    }
    if (j + 4 <= m) {
        int c0 = bucket[(j + 0) * n + nd], c1 = bucket[(j + 1) * n + nd];
        int c2 = bucket[(j + 2) * n + nd], c3 = bucket[(j + 3) * n + nd];
        float n0 = dinv[c0], n1 = dinv[c1], n2 = dinv[c2], n3 = dinv[c3];
        unsigned u0 = hu[(long)c0 * 64 + lane], u1 = hu[(long)c1 * 64 + lane];
        unsigned u2 = hu[(long)c2 * 64 + lane], u3 = hu[(long)c3 * 64 + lane];
        AGG_STEP(n0, u0) AGG_STEP(n1, u1) AGG_STEP(n2, u2) AGG_STEP(n3, u3)
        j += 4;
    }
    for (; j < m; ++j) {
        int c = bucket[j * n + nd];
        float nr = dinv[c];
        unsigned u = hu[(long)c * 64 + lane];
        AGG_STEP(nr, u)
    }
    if (do_relu) { ax = fmaxf(ax, 0.f); ay = fmaxf(ay, 0.f); }
    if (OUT_BF16) {
        ((unsigned*)outv)[(long)nd * 64 + lane] = (unsigned)f2bf(ax) | ((unsigned)f2bf(ay) << 16);
    } else {
        float2 o; o.x = ax; o.y = ay;
        ((float2*)outv)[(long)nd * 64 + lane] = o;
    }
}

// ---------------- atomic-scatter fallback ----------------

__global__ __launch_bounds__(256) void k_edge_deg_i(const int* __restrict__ col, int* degi, int ne) {
    int e = blockIdx.x * 256 + threadIdx.x;
    if (e >= ne) return;
    atomicAdd(&degi[col[e]], 1);
}

__global__ __launch_bounds__(256) void k_selfinit(const unsigned* __restrict__ hu, const float* __restrict__ dinv,
                                                  float* __restrict__ g, int n) {
    long i = (long)blockIdx.x * 256 + threadIdx.x;
    if (i >= (long)n * 64) return;
    int node = (int)(i >> 6);
    float d = dinv[node];
    unsigned u = hu[i];
    float2 o; o.x = d * d * bflo(u); o.y = d * d * bfhi(u);
    ((float2*)g)[i] = o;
}

__global__ __launch_bounds__(256) void k_scatter(const int* __restrict__ row, const int* __restrict__ col,
                                                 const float* __restrict__ dinv, const unsigned* __restrict__ hu,
                                                 float* __restrict__ g, int ne) {
    int e = blockIdx.x * 4 + (threadIdx.x >> 6);
    int lane = threadIdx.x & 63;
    if (e >= ne) return;
    int r = row[e], c = col[e];
    float nrm = dinv[r] * dinv[c];
    unsigned u = hu[(long)c * 64 + lane];
    atomicAdd(&g[(long)r * 128 + lane * 2], nrm * bflo(u));
    atomicAdd(&g[(long)r * 128 + lane * 2 + 1], nrm * bfhi(u));
}

__global__ __launch_bounds__(256) void k_reluf2bf(const float* __restrict__ g, unsigned* __restrict__ g16, long n2) {
    long i = (long)blockIdx.x * 256 + threadIdx.x;
    if (i >= n2) return;
    float2 v = ((const float2*)g)[i];
    g16[i] = (unsigned)f2bf(fmaxf(v.x, 0.f)) | ((unsigned)f2bf(fmaxf(v.y, 0.f)) << 16);
}

__global__ __launch_bounds__(256) void k_f32tobf(const float* __restrict__ g, unsigned* __restrict__ g16, long n2) {
    long i = (long)blockIdx.x * 256 + threadIdx.x;
    if (i >= n2) return;
    float2 v = ((const float2*)g)[i];
    g16[i] = (unsigned)f2bf(v.x) | ((unsigned)f2bf(v.y) << 16);
}

// ---------------- mean pool (two-stage, bf16 input) ----------------

__global__ __launch_bounds__(256) void k_pool_partial_bf16(const unsigned* __restrict__ g16,
                                                           const int* __restrict__ batch,
                                                           int n, float* __restrict__ partial, int* __restrict__ cntg) {
    int gid = blockIdx.x >> 3;
    int s   = blockIdx.x & 7;
    int t = threadIdx.x;
    int lo = 0, hi = n;
    while (lo < hi) { int m = (lo + hi) >> 1; if (batch[m] < gid) lo = m + 1; else hi = m; }
    int s0 = lo;
    hi = n;
    while (lo < hi) { int m = (lo + hi) >> 1; if (batch[m] < gid + 1) lo = m + 1; else hi = m; }
    int e0 = lo;
    if (s == 0 && t == 0) cntg[gid] = e0 - s0;

    int lane = t & 63, wid = t >> 6;
    float ax = 0.f, ay = 0.f;
    for (int i = s0 + s * 4 + wid; i < e0; i += 32) {
        unsigned u = g16[(long)i * 64 + lane];
        ax += bflo(u); ay += bfhi(u);
    }
    __shared__ float2 red[256];
    red[t] = make_float2(ax, ay);
    __syncthreads();
    if (t < 64) {
        float2 a = red[t];
#pragma unroll
        for (int r = 1; r < 4; ++r) {
            float2 b = red[r * 64 + t];
            a.x += b.x; a.y += b.y;
        }
        ((float2*)partial)[(long)blockIdx.x * 64 + t] = a;
    }
}

__global__ __launch_bounds__(256) void k_pool_final(const float* __restrict__ partial, const int* __restrict__ cntg,
                                                    int ng, float* __restrict__ out) {
    int idx = blockIdx.x * 256 + threadIdx.x;
    if (idx >= ng * 128) return;
    int gid = idx >> 7, col = idx & 127;
    float a = 0.f;
#pragma unroll
    for (int s = 0; s < POOL_S; ++s) a += partial[(long)(gid * POOL_S + s) * 128 + col];
    out[idx] = a / fmaxf((float)cntg[gid], 1.0f);
}

// ---------------- host ----------------

extern "C" void kernel_launch(void* const* d_in, const int* in_sizes, int n_in,
                              void* d_out, int out_size, void* d_ws, size_t ws_size,
                              hipStream_t stream) {
    const float* x  = (const float*)d_in[0];
    const int* ei   = (const int*)d_in[1];
    const int* batch = (const int*)d_in[2];
    const float* W1 = (const float*)d_in[4];
    const float* b1 = (const float*)d_in[5];
    const float* W2 = (const float*)d_in[6];
    const float* b2 = (const float*)d_in[7];

    int N = in_sizes[0] / 128;
    int E = in_sizes[1] / 2;
    const int* row = ei;
    const int* col = ei + E;
    int G = out_size / 128;

    char* ws = (char*)d_ws;
    size_t off = 0;
    auto alloc = [&](size_t bytes) -> void* {
        void* p = ws + off;
        off += (bytes + 255) & ~(size_t)255;
        return p;
    };
    int* degi   = (int*)alloc((size_t)N * 4);
    float* dinv = (float*)alloc((size_t)N * 4);
    int* cnt    = (int*)alloc((size_t)N * 4);
    unsigned short* h = (unsigned short*)alloc((size_t)N * 256);   // bf16 h (gemm out)
    float* g    = (float*)alloc((size_t)N * 512);                  // agg out
    float* partial = (float*)alloc((size_t)G * POOL_S * 128 * 4);
    int* cntg   = (int*)alloc((size_t)G * 4);
    uint4* wp1  = (uint4*)alloc(32768);
    uint4* wp2  = (uint4*)alloc(32768);
    size_t bucket_bytes = (size_t)N * CAP * 4;
    bool use_bucket = (off + bucket_bytes) <= ws_size;
    int* bucket = use_bucket ? (int*)alloc(bucket_bytes) : nullptr;

    int nbN = (N + 255) / 256;
    int gemm_blocks = (N + 63) / 64;
    int agg_blocks  = (N + 3) / 4;
    int edge_blocks = (E + 1023) / 1024;

    k_prep<<<nbN, 256, 0, stream>>>(W1, W2, wp1, wp2, degi, cnt, N);

    if (use_bucket) {
        k_edge_gemm1<<<edge_blocks + gemm_blocks, 256, 0, stream>>>(
            x, (const float4*)wp1, b1, h, N, edge_blocks, row, col, degi, cnt, bucket, E);
        k_dinv<<<nbN, 256, 0, stream>>>(degi, dinv, N);
        k_agg<1><<<agg_blocks, 256, 0, stream>>>((const unsigned*)h, dinv, cnt, bucket, g, N, 1);
        k_gemm_mfma<1><<<gemm_blocks, 256, 0, stream>>>(g, (const float4*)wp2, b2, h, N);
        k_agg<1><<<agg_blocks, 256, 0, stream>>>((const unsigned*)h, dinv, cnt, bucket, g, N, 0);
        k_pool_partial_bf16<<<G * POOL_S, 256, 0, stream>>>((const unsigned*)g, batch, N, partial, cntg);
    } else {
        k_edge_deg_i<<<(E + 255) / 256, 256, 0, stream>>>(col, degi, E);
        k_dinv<<<nbN, 256, 0, stream>>>(degi, dinv, N);
        k_gemm_mfma<0><<<gemm_blocks, 256, 0, stream>>>(x, (const float4*)wp1, b1, h, N);
        k_selfinit<<<(int)(((long)N * 64 + 255) / 256), 256, 0, stream>>>((const unsigned*)h, dinv, g, N);
        k_scatter<<<(E + 3) / 4, 256, 0, stream>>>(row, col, dinv, (const unsigned*)h, g, E);
        k_reluf2bf<<<(int)(((long)N * 64 + 255) / 256), 256, 0, stream>>>(g, (unsigned*)h, (long)N * 64);
        k_gemm_mfma<1><<<gemm_blocks, 256, 0, stream>>>(h, (const float4*)wp2, b2, h, N);
        k_selfinit<<<(int)(((long)N * 64 + 255) / 256), 256, 0, stream>>>((const unsigned*)h, dinv, g, N);
        k_scatter<<<(E + 3) / 4, 256, 0, stream>>>(row, col, dinv, (const unsigned*)h, g, E);
        k_f32tobf<<<(int)(((long)N * 64 + 255) / 256), 256, 0, stream>>>(g, (unsigned*)g, (long)N * 64);
        k_pool_partial_bf16<<<G * POOL_S, 256, 0, stream>>>((const unsigned*)g, batch, N, partial, cntg);
    }

    k_pool_final<<<(G * 128 + 255) / 256, 256, 0, stream>>>(partial, cntg, G, (float*)d_out);
}